// Round 10
// baseline (550.105 us; speedup 1.0000x reference)
//
#include <hip/hip_runtime.h>
#include <hip/hip_bf16.h>

#define U_CNT 200000
#define I_CNT 100000
#define N_CNT 300000
#define E_CNT 1000000
#define ATTR_D 8
#define H_DIM 32
#define NB_SCAN ((N_CNT + 255) / 256)
#define IB 128                               // items per item-block
#define NB_I ((I_CNT + IB - 1) / IB)         // 782 item blocks
#define NB_META (I_CNT / 16)                 // 6250 blocks, 16 items/block
#define XP 130                               // sXT pitch (bf16 elems)

// binning parameters
#define BSHIFT 10                            // 1024 nodes per bucket
#define NBUCK 293                            // ceil(300000/1024)
#define BCAP 12288                           // entries capacity/bucket (>20 sigma)
#define EPB 2048                             // edges per bin1 block
#define NB_BIN1 ((E_CNT + EPB - 1) / EPB)    // 489

// NOTE (rounds 1-4): all float inputs / output FLOAT32. absmax floor 1.95e-3
// == bf16 rounding of reference; threshold 1.26e-2.
// NOTE (round 7): rank-capture scatter + y-space reform. 1098 -> 951 us.
// NOTE (round 8/13/14): k_items LDS GEMM; real fix was splitting serial
// meta-gather into k_meta (4 rows/vmem instr).
// NOTE (round 9): bf16 y-storage. round 10: k_prop 4 nodes/wave (4x in-flight
// gathers) 830 -> 634. GATHERS = latency x concurrency.
// NOTE (round 11): fusion regressed (LDS throttled atomic occupancy).
// NOTE (round 12): per-thread batching regressed for ATOMICS.
// NOTE (round 15): 2-phase bucket binning CSR build (replaced edge_mlp +
// scans + scatter). 615 -> 547, matched.
// NOTE (round 16, this round): bin kernels were GRID-STARVED (bin1: 489
// blocks x 4 waves = 24% occ cap; bin2: 293 x 8 = 28%). bin1 -> 512 thr
// (8 waves/block, ~48% cap), bin2 -> 1024 thr (~57% cap). k_prop main loop
// unroll 4 -> 8 (8 in-flight gathers/wave; VGPR=16 had headroom).

typedef unsigned short ubf;

__device__ __forceinline__ float b2f(ubf b) {
    return __uint_as_float((unsigned)b << 16);
}
__device__ __forceinline__ ubf f2b(float v) {
    unsigned u = __float_as_uint(v);
    u += 0x7fffu + ((u >> 16) & 1u);           // round to nearest even
    return (ubf)(u >> 16);
}
__device__ __forceinline__ unsigned pk2(float lo, float hi) {
    return (unsigned)f2b(lo) | ((unsigned)f2b(hi) << 16);
}
__device__ __forceinline__ float4 b4f(ushort4 u) {
    return make_float4(b2f(u.x), b2f(u.y), b2f(u.z), b2f(u.w));
}
// entry pack: x = key[0:19) | (partner&0x1FFF)<<19 ; y = partner>>13 | wb<<16
__device__ __forceinline__ uint2 packE(int key, int partner, unsigned wb) {
    return make_uint2((unsigned)key | (((unsigned)partner & 0x1FFFu) << 19),
                     ((unsigned)partner >> 13) | (wb << 16));
}

// ---------------- init bucket cursors ----------------
__global__ void k_init(int* __restrict__ gcur) {
    int i = blockIdx.x * 256 + threadIdx.x;
    if (i < NBUCK) gcur[i] = i * BCAP;
}

// ---------------- phase 1: edge MLP + bucket binning (512 thr, 4 edges/thr) ----------------
__global__ void __launch_bounds__(512)
k_bin1(const int* __restrict__ src, const int* __restrict__ dst,
       const float* __restrict__ attr,
       const float* __restrict__ W1, const float* __restrict__ b1,
       const float* __restrict__ W2, const float* __restrict__ b2,
       uint2* __restrict__ ebuf, int* __restrict__ gcur) {
    __shared__ float sW1[ATTR_D * H_DIM];
    __shared__ float sb1[H_DIM];
    __shared__ float sW2[H_DIM];
    __shared__ float sb2;
    __shared__ int hist[NBUCK];
    __shared__ int basem[NBUCK];
    int t = threadIdx.x;
    if (t < 256) sW1[t] = W1[t];
    if (t < H_DIM) { sb1[t] = b1[t]; sW2[t] = W2[t]; }
    if (t == 0) sb2 = b2[0];
    for (int i = t; i < NBUCK; i += 512) hist[i] = 0;
    __syncthreads();
    int ebase = blockIdx.x * EPB;
    int sarr[4], darr[4];
    unsigned warr[4];
    #pragma unroll
    for (int k = 0; k < 4; ++k) {
        int e = ebase + k * 512 + t;
        sarr[k] = -1;
        if (e < E_CNT) {
            const float4* a4 = (const float4*)attr + (size_t)e * 2;
            float4 r0 = a4[0];
            float4 r1 = a4[1];
            float a[8] = {r0.x, r0.y, r0.z, r0.w, r1.x, r1.y, r1.z, r1.w};
            float z = sb2;
            #pragma unroll
            for (int h = 0; h < H_DIM; ++h) {
                float acc = sb1[h];
                #pragma unroll
                for (int kk = 0; kk < 8; ++kk) acc = fmaf(a[kk], sW1[kk * H_DIM + h], acc);
                acc = fmaxf(acc, 0.0f);
                z = fmaf(acc, sW2[h], z);
            }
            float w = 1.0f / (1.0f + __expf(-z));
            w = fmaxf(w, 1e-6f);
            int s = src[e], d = U_CNT + dst[e];
            sarr[k] = s; darr[k] = d; warr[k] = (unsigned)f2b(w);
            atomicAdd(&hist[s >> BSHIFT], 1);
            atomicAdd(&hist[d >> BSHIFT], 1);
        }
    }
    __syncthreads();
    for (int i = t; i < NBUCK; i += 512) {
        int h = hist[i];
        basem[i] = (h > 0) ? atomicAdd(&gcur[i], h) : 0;
    }
    __syncthreads();
    for (int i = t; i < NBUCK; i += 512) hist[i] = 0;   // reuse as cursor
    __syncthreads();
    #pragma unroll
    for (int k = 0; k < 4; ++k) {
        if (sarr[k] >= 0) {
            int s = sarr[k], d = darr[k];
            unsigned wb = warr[k];
            int bs = s >> BSHIFT;
            int r = atomicAdd(&hist[bs], 1);
            ebuf[(size_t)basem[bs] + r] = packE(s, d, wb);
            int bd = d >> BSHIFT;
            r = atomicAdd(&hist[bd], 1);
            ebuf[(size_t)basem[bd] + r] = packE(d, s, wb);
        }
    }
}

// ---------------- phase 2: per-bucket CSR build (1024 thr, offs + csr) ----------------
__global__ void __launch_bounds__(1024)
k_bin2(const uint2* __restrict__ ebuf, const int* __restrict__ gcur,
       int* __restrict__ offs, int2* __restrict__ csr) {
    __shared__ int ldsCnt[NBUCK];
    __shared__ int ldsH[1024];
    __shared__ int ldsC[1024];
    __shared__ int ldsT[1024];
    __shared__ int sMeta[2];          // csr_base, mycount
    int t = threadIdx.x;
    int b = blockIdx.x;
    if (t < NBUCK) ldsCnt[t] = gcur[t] - t * BCAP;
    ldsH[t] = 0;
    ldsC[t] = 0;
    __syncthreads();
    if (t == 0) {
        int base = 0;
        for (int i = 0; i < b; ++i) base += ldsCnt[i];
        sMeta[0] = base;
        sMeta[1] = ldsCnt[b];
    }
    __syncthreads();
    int csr_base = sMeta[0], mycount = sMeta[1];
    size_t eb = (size_t)b * BCAP;
    int first = b << BSHIFT;
    // node histogram
    for (int i = t; i < mycount; i += 1024) {
        uint2 en = ebuf[eb + i];
        atomicAdd(&ldsH[(en.x & 0x7FFFFu) - first], 1);
    }
    __syncthreads();
    // exclusive scan of 1024 counters (1024 threads, Hillis-Steele)
    int v0 = ldsH[t];
    ldsT[t] = v0;
    __syncthreads();
    #pragma unroll
    for (int off = 1; off < 1024; off <<= 1) {
        int x = (t >= off) ? ldsT[t - off] : 0;
        __syncthreads();
        ldsT[t] += x;
        __syncthreads();
    }
    int excl = ldsT[t] - v0;
    ldsH[t] = excl;                   // ldsH now exclusive offsets
    __syncthreads();
    int ncnt = min(1024, N_CNT - first);
    if (t < ncnt) offs[first + t] = csr_base + ldsH[t];
    if (b == NBUCK - 1 && t == 0) offs[N_CNT] = 2 * E_CNT;
    // scatter entries to final CSR (L2-local span)
    for (int i = t; i < mycount; i += 1024) {
        uint2 en = ebuf[eb + i];
        int key = (int)(en.x & 0x7FFFFu);
        int partner = (int)((en.x >> 19) | ((en.y & 0xFFFFu) << 13));
        unsigned wb = en.y >> 16;
        int li = key - first;
        int r = atomicAdd(&ldsC[li], 1);
        csr[csr_base + ldsH[li] + r] = make_int2(partner, (int)(wb << 16));
    }
}

// ---------------- deg via segment sum (no atomics), dis = rsqrt(1+sum) ----------------
__global__ void k_deg(const int* __restrict__ offs, const int2* __restrict__ csr,
                      float* __restrict__ dis) {
    int i = blockIdx.x * 256 + threadIdx.x;
    if (i >= N_CNT) return;
    int b = offs[i], e = offs[i + 1];
    float s = 1.0f;                      // self loop weight
    for (int k = b; k < e; ++k) s += __int_as_float(csr[k].y);
    dis[i] = rsqrtf(s);                  // s >= 1 always
}

// ---------------- users: y0 = dis * l2norm(user_w) ----------------
__global__ void k_users(const float* __restrict__ user_w, const float* __restrict__ dis,
                        ubf* __restrict__ y0, float* __restrict__ acc, int use_acc) {
    int lane = threadIdx.x & 63;
    int wv = (blockIdx.x * blockDim.x + threadIdx.x) >> 6;
    int nw = (gridDim.x * blockDim.x) >> 6;
    for (int r = wv; r < U_CNT; r += nw) {
        int idx = r * 64 + lane;
        float v = user_w[idx];
        float ss = v * v;
        #pragma unroll
        for (int m = 32; m >= 1; m >>= 1) ss += __shfl_xor(ss, m, 64);
        float inv = dis[r] / fmaxf(sqrtf(ss), 1e-12f);
        float o = v * inv;
        y0[idx] = f2b(o);
        if (use_acc) acc[idx] = o;
    }
}

// ---------------- meta gather: 4 items/wave, 16 lanes/item, float4/lane ----------------
__global__ void k_meta(const float* __restrict__ art, const float* __restrict__ alb,
                       const int* __restrict__ aid, const int* __restrict__ alid,
                       ubf* __restrict__ metabuf) {
    int t = threadIdx.x;
    int lane = t & 63;
    int g = lane >> 4;                   // item group 0..3
    int q = lane & 15;                   // float4 slot within 256B row
    int wv = (blockIdx.x * 256 + t) >> 6;
    int it = wv * 4 + g;
    if (it >= I_CNT) return;
    int a_ = aid[it], al_ = alid[it];
    float4 va = *(const float4*)&art[(size_t)a_ * 64 + q * 4];
    float4 vb = *(const float4*)&alb[(size_t)al_ * 64 + q * 4];
    ushort4 o = make_ushort4(f2b(va.x + vb.x), f2b(va.y + vb.y),
                             f2b(va.z + vb.z), f2b(va.w + vb.w));
    *(ushort4*)&metabuf[(size_t)it * 64 + q * 4] = o;
}

// ---------------- items: pure-streaming bf16-LDS GEMM, 4 items x 8 outs ----------------
__global__ void __launch_bounds__(256)
k_items(const float* __restrict__ audio, const ubf* __restrict__ metabuf,
        const float* __restrict__ Wp, const float* __restrict__ bp,
        const float* __restrict__ dis,
        ubf* __restrict__ yitem, float* __restrict__ accitem, int use_acc) {
    __shared__ __align__(16) ubf sXT[128 * XP];
    __shared__ __align__(16) ubf sW[128 * 64];
    int t = threadIdx.x;
    int base = blockIdx.x * IB;
    // stage Wp -> bf16
    {
        const float4* wg = (const float4*)Wp;
        #pragma unroll
        for (int r = 0; r < 8; ++r) {
            int idx = r * 256 + t;
            float4 v = wg[idx];
            ushort4 o = make_ushort4(f2b(v.x), f2b(v.y), f2b(v.z), f2b(v.w));
            *(ushort4*)&sW[idx * 4] = o;
        }
    }
    // stage audio -> sXT[f][i] transposed
    {
        const float4* g = (const float4*)audio + (size_t)base * 16;
        #pragma unroll
        for (int r = 0; r < 8; ++r) {
            int idx = r * 256 + t;               // 0..2047
            int i = idx >> 4, fq = idx & 15;
            float4 v = make_float4(0.f, 0.f, 0.f, 0.f);
            if (base + i < I_CNT) v = g[idx];
            sXT[(4 * fq + 0) * XP + i] = f2b(v.x);
            sXT[(4 * fq + 1) * XP + i] = f2b(v.y);
            sXT[(4 * fq + 2) * XP + i] = f2b(v.z);
            sXT[(4 * fq + 3) * XP + i] = f2b(v.w);
        }
    }
    // stage metabuf -> sXT[64+f][i]
    {
        const uint4* m4 = (const uint4*)(metabuf + (size_t)base * 64);
        #pragma unroll
        for (int r = 0; r < 4; ++r) {
            int idx = r * 256 + t;               // 0..1023
            int i = idx >> 3, c = idx & 7;
            uint4 m = make_uint4(0u, 0u, 0u, 0u);
            if (base + i < I_CNT) m = m4[idx];
            ubf* dp = &sXT[(64 + 8 * c) * XP + i];
            dp[0 * XP] = (ubf)(m.x & 0xffffu); dp[1 * XP] = (ubf)(m.x >> 16);
            dp[2 * XP] = (ubf)(m.y & 0xffffu); dp[3 * XP] = (ubf)(m.y >> 16);
            dp[4 * XP] = (ubf)(m.z & 0xffffu); dp[5 * XP] = (ubf)(m.z >> 16);
            dp[6 * XP] = (ubf)(m.w & 0xffffu); dp[7 * XP] = (ubf)(m.w >> 16);
        }
    }
    __syncthreads();
    int og = t & 7;                      // outs 8og..8og+7
    int igr = t >> 3;                    // items 4igr..4igr+3
    float c[4][8];
    {
        float bv[8];
        #pragma unroll
        for (int j = 0; j < 8; ++j) bv[j] = bp[8 * og + j];
        #pragma unroll
        for (int i = 0; i < 4; ++i)
            #pragma unroll
            for (int j = 0; j < 8; ++j) c[i][j] = bv[j];
    }
    const ubf* xcol = &sXT[4 * igr];
    const ubf* wrow = &sW[8 * og];
    #pragma unroll 2
    for (int k = 0; k < 128; ++k) {
        ushort4 xu = *(const ushort4*)&xcol[k * XP];
        uint4 wu = *(const uint4*)&wrow[k * 64];
        float x[4] = {b2f(xu.x), b2f(xu.y), b2f(xu.z), b2f(xu.w)};
        float w[8];
        w[0] = __uint_as_float(wu.x << 16); w[1] = __uint_as_float(wu.x & 0xffff0000u);
        w[2] = __uint_as_float(wu.y << 16); w[3] = __uint_as_float(wu.y & 0xffff0000u);
        w[4] = __uint_as_float(wu.z << 16); w[5] = __uint_as_float(wu.z & 0xffff0000u);
        w[6] = __uint_as_float(wu.w << 16); w[7] = __uint_as_float(wu.w & 0xffff0000u);
        #pragma unroll
        for (int i = 0; i < 4; ++i)
            #pragma unroll
            for (int j = 0; j < 8; ++j) c[i][j] = fmaf(x[i], w[j], c[i][j]);
    }
    #pragma unroll
    for (int i = 0; i < 4; ++i) {
        float ss = 0.f;
        #pragma unroll
        for (int j = 0; j < 8; ++j) ss += c[i][j] * c[i][j];
        ss += __shfl_xor(ss, 1, 64);
        ss += __shfl_xor(ss, 2, 64);
        ss += __shfl_xor(ss, 4, 64);
        int it = base + 4 * igr + i;
        if (it < I_CNT) {
            float q = dis[U_CNT + it] / fmaxf(sqrtf(ss), 1e-12f);
            uint4 o;
            o.x = pk2(c[i][0] * q, c[i][1] * q);
            o.y = pk2(c[i][2] * q, c[i][3] * q);
            o.z = pk2(c[i][4] * q, c[i][5] * q);
            o.w = pk2(c[i][6] * q, c[i][7] * q);
            *(uint4*)&yitem[(size_t)it * 64 + 8 * og] = o;
            if (use_acc) {
                float4* ap = (float4*)&accitem[(size_t)it * 64 + 8 * og];
                ap[0] = make_float4(c[i][0] * q, c[i][1] * q, c[i][2] * q, c[i][3] * q);
                ap[1] = make_float4(c[i][4] * q, c[i][5] * q, c[i][6] * q, c[i][7] * q);
            }
        }
    }
}

// ---------------- LGConv round: 4 nodes/wave, 16 lanes/node, unroll-8 ----------------
__global__ void k_prop(const int* __restrict__ offs, const int2* __restrict__ csr,
                       const float* __restrict__ dis,
                       const ubf* __restrict__ yin, ubf* __restrict__ yout,
                       float* __restrict__ acc, int use_acc) {
    int lane = threadIdx.x & 63;
    int g = lane >> 4;                   // node group 0..3
    int s4 = (lane & 15) * 4;            // dims s4..s4+3
    int wv = (blockIdx.x * 256 + threadIdx.x) >> 6;
    int c = wv * 4 + g;
    if (c >= N_CNT) return;
    int e = offs[c], end = offs[c + 1];
    float dc = dis[c];
    float4 a0 = make_float4(0.f, 0.f, 0.f, 0.f);
    float4 a1 = a0, a2 = a0, a3 = a0;
    for (; e + 7 < end; e += 8) {
        int2 e0 = csr[e], e1 = csr[e + 1], e2 = csr[e + 2], e3 = csr[e + 3];
        int2 e4 = csr[e + 4], e5 = csr[e + 5], e6 = csr[e + 6], e7 = csr[e + 7];
        ushort4 g0 = *(const ushort4*)&yin[(size_t)e0.x * 64 + s4];
        ushort4 g1 = *(const ushort4*)&yin[(size_t)e1.x * 64 + s4];
        ushort4 g2 = *(const ushort4*)&yin[(size_t)e2.x * 64 + s4];
        ushort4 g3 = *(const ushort4*)&yin[(size_t)e3.x * 64 + s4];
        ushort4 g4 = *(const ushort4*)&yin[(size_t)e4.x * 64 + s4];
        ushort4 g5 = *(const ushort4*)&yin[(size_t)e5.x * 64 + s4];
        ushort4 g6 = *(const ushort4*)&yin[(size_t)e6.x * 64 + s4];
        ushort4 g7 = *(const ushort4*)&yin[(size_t)e7.x * 64 + s4];
        float w0 = __int_as_float(e0.y), w1 = __int_as_float(e1.y);
        float w2 = __int_as_float(e2.y), w3 = __int_as_float(e3.y);
        float w4 = __int_as_float(e4.y), w5 = __int_as_float(e5.y);
        float w6 = __int_as_float(e6.y), w7 = __int_as_float(e7.y);
        float4 f0 = b4f(g0), f1 = b4f(g1), f2 = b4f(g2), f3 = b4f(g3);
        float4 f4 = b4f(g4), f5 = b4f(g5), f6 = b4f(g6), f7 = b4f(g7);
        a0.x = fmaf(w0, f0.x, a0.x); a0.y = fmaf(w0, f0.y, a0.y);
        a0.z = fmaf(w0, f0.z, a0.z); a0.w = fmaf(w0, f0.w, a0.w);
        a1.x = fmaf(w1, f1.x, a1.x); a1.y = fmaf(w1, f1.y, a1.y);
        a1.z = fmaf(w1, f1.z, a1.z); a1.w = fmaf(w1, f1.w, a1.w);
        a2.x = fmaf(w2, f2.x, a2.x); a2.y = fmaf(w2, f2.y, a2.y);
        a2.z = fmaf(w2, f2.z, a2.z); a2.w = fmaf(w2, f2.w, a2.w);
        a3.x = fmaf(w3, f3.x, a3.x); a3.y = fmaf(w3, f3.y, a3.y);
        a3.z = fmaf(w3, f3.z, a3.z); a3.w = fmaf(w3, f3.w, a3.w);
        a0.x = fmaf(w4, f4.x, a0.x); a0.y = fmaf(w4, f4.y, a0.y);
        a0.z = fmaf(w4, f4.z, a0.z); a0.w = fmaf(w4, f4.w, a0.w);
        a1.x = fmaf(w5, f5.x, a1.x); a1.y = fmaf(w5, f5.y, a1.y);
        a1.z = fmaf(w5, f5.z, a1.z); a1.w = fmaf(w5, f5.w, a1.w);
        a2.x = fmaf(w6, f6.x, a2.x); a2.y = fmaf(w6, f6.y, a2.y);
        a2.z = fmaf(w6, f6.z, a2.z); a2.w = fmaf(w6, f6.w, a2.w);
        a3.x = fmaf(w7, f7.x, a3.x); a3.y = fmaf(w7, f7.y, a3.y);
        a3.z = fmaf(w7, f7.z, a3.z); a3.w = fmaf(w7, f7.w, a3.w);
    }
    for (; e + 3 < end; e += 4) {
        int2 e0 = csr[e], e1 = csr[e + 1], e2 = csr[e + 2], e3 = csr[e + 3];
        ushort4 g0 = *(const ushort4*)&yin[(size_t)e0.x * 64 + s4];
        ushort4 g1 = *(const ushort4*)&yin[(size_t)e1.x * 64 + s4];
        ushort4 g2 = *(const ushort4*)&yin[(size_t)e2.x * 64 + s4];
        ushort4 g3 = *(const ushort4*)&yin[(size_t)e3.x * 64 + s4];
        float w0 = __int_as_float(e0.y), w1 = __int_as_float(e1.y);
        float w2 = __int_as_float(e2.y), w3 = __int_as_float(e3.y);
        float4 f0 = b4f(g0), f1 = b4f(g1), f2 = b4f(g2), f3 = b4f(g3);
        a0.x = fmaf(w0, f0.x, a0.x); a0.y = fmaf(w0, f0.y, a0.y);
        a0.z = fmaf(w0, f0.z, a0.z); a0.w = fmaf(w0, f0.w, a0.w);
        a1.x = fmaf(w1, f1.x, a1.x); a1.y = fmaf(w1, f1.y, a1.y);
        a1.z = fmaf(w1, f1.z, a1.z); a1.w = fmaf(w1, f1.w, a1.w);
        a2.x = fmaf(w2, f2.x, a2.x); a2.y = fmaf(w2, f2.y, a2.y);
        a2.z = fmaf(w2, f2.z, a2.z); a2.w = fmaf(w2, f2.w, a2.w);
        a3.x = fmaf(w3, f3.x, a3.x); a3.y = fmaf(w3, f3.y, a3.y);
        a3.z = fmaf(w3, f3.z, a3.z); a3.w = fmaf(w3, f3.w, a3.w);
    }
    for (; e < end; ++e) {
        int2 ee = csr[e];
        ushort4 gg = *(const ushort4*)&yin[(size_t)ee.x * 64 + s4];
        float ww = __int_as_float(ee.y);
        float4 ff = b4f(gg);
        a0.x = fmaf(ww, ff.x, a0.x); a0.y = fmaf(ww, ff.y, a0.y);
        a0.z = fmaf(ww, ff.z, a0.z); a0.w = fmaf(ww, ff.w, a0.w);
    }
    size_t idx = (size_t)c * 64 + s4;
    float4 self = b4f(*(const ushort4*)&yin[idx]);
    float dc2 = dc * dc;
    float4 r;
    r.x = dc2 * (((a0.x + a1.x) + (a2.x + a3.x)) + self.x);
    r.y = dc2 * (((a0.y + a1.y) + (a2.y + a3.y)) + self.y);
    r.z = dc2 * (((a0.z + a1.z) + (a2.z + a3.z)) + self.z);
    r.w = dc2 * (((a0.w + a1.w) + (a2.w + a3.w)) + self.w);
    *(ushort4*)&yout[idx] = make_ushort4(f2b(r.x), f2b(r.y), f2b(r.z), f2b(r.w));
    if (use_acc) {
        float4* ap = (float4*)&acc[idx];
        float4 av = *ap;
        av.x += r.x; av.y += r.y; av.z += r.z; av.w += r.w;
        *ap = av;
    }
}

// ---------------- epilogue A: l2norm(acc)  (acc fp32, may alias out) ----------------
__global__ void k_final_acc(const float* __restrict__ acc, float* __restrict__ out) {
    int lane = threadIdx.x & 63;
    int c = (blockIdx.x * 256 + threadIdx.x) >> 6;
    if (c >= N_CNT) return;
    int idx = c * 64 + lane;
    float v = acc[idx];
    float ss = v * v;
    #pragma unroll
    for (int m = 32; m >= 1; m >>= 1) ss += __shfl_xor(ss, m, 64);
    out[idx] = v / fmaxf(sqrtf(ss), 1e-12f);
}

// ---------------- epilogue B: l2norm(y0+y1+y2+y3), all bf16 ----------------
__global__ void k_final_sum(const ubf* __restrict__ y0, const ubf* __restrict__ y1,
                            const ubf* __restrict__ y2, const ubf* __restrict__ y3,
                            float* __restrict__ out) {
    int lane = threadIdx.x & 63;
    int c = (blockIdx.x * 256 + threadIdx.x) >> 6;
    if (c >= N_CNT) return;
    int idx = c * 64 + lane;
    float v = b2f(y0[idx]) + b2f(y1[idx]) + b2f(y2[idx]) + b2f(y3[idx]);
    float ss = v * v;
    #pragma unroll
    for (int m = 32; m >= 1; m >>= 1) ss += __shfl_xor(ss, m, 64);
    out[idx] = v / fmaxf(sqrtf(ss), 1e-12f);
}

extern "C" void kernel_launch(void* const* d_in, const int* in_sizes, int n_in,
                              void* d_out, int out_size, void* d_ws, size_t ws_size,
                              hipStream_t stream) {
    const int*   edge_src   = (const int*)  d_in[0];
    const int*   edge_dst   = (const int*)  d_in[1];
    const float* edge_attr  = (const float*)d_in[2];
    const float* user_w     = (const float*)d_in[3];
    const float* artist_w   = (const float*)d_in[4];
    const float* album_w    = (const float*)d_in[5];
    const float* item_audio = (const float*)d_in[6];
    const int*   artist_ids = (const int*)  d_in[7];
    const int*   album_ids  = (const int*)  d_in[8];
    const float* Wp         = (const float*)d_in[9];
    const float* bp         = (const float*)d_in[10];
    const float* W1         = (const float*)d_in[11];
    const float* b1         = (const float*)d_in[12];
    const float* W2         = (const float*)d_in[13];
    const float* b2         = (const float*)d_in[14];

    char* p = (char*)d_ws;
    auto carve = [&](size_t bytes) -> void* {
        void* q = (void*)p;
        p += (bytes + 255) & ~(size_t)255;
        return q;
    };
    // common carve (~31 MB)
    float* dis    = (float*)carve((size_t)N_CNT * 4);
    int*   offs   = (int*)  carve((size_t)(N_CNT + 1) * 4);
    int*   gcur   = (int*)  carve((size_t)NBUCK * 4);
    int2*  csr    = (int2*) carve((size_t)2 * E_CNT * 8);
    ubf*   metabuf= (ubf*)  carve((size_t)I_CNT * 64 * 2);  // 12.8 MB bf16
    const size_t YB = (size_t)N_CNT * 64 * 2;      // 38.4 MB per bf16 y buffer
    const size_t EBUF = (size_t)NBUCK * BCAP * 8;  // 28.8 MB entry buffer
    size_t used = (size_t)(p - (char*)d_ws);
    // Path B (no acc RMW) needs y0..y3 bf16 in ws; ebuf aliases y2/y3
    // (dead before prop round 2). Else ping-pong + fp32 acc in d_out.
    int no_acc = (ws_size >= used + 4 * YB + (size_t)4096) ? 1 : 0;
    ubf *y0, *y1, *y2, *y3;
    uint2* ebuf;
    float* acc = nullptr;
    if (no_acc) {
        y0 = (ubf*)carve(YB);
        y1 = (ubf*)carve(YB);
        y2 = (ubf*)carve(YB);
        y3 = (ubf*)carve(YB);
        ebuf = (uint2*)y2;             // alias: y2+y3 = 76.8MB >= 28.8MB
    } else {
        y0 = (ubf*)carve(YB);
        y1 = (ubf*)carve(YB);
        y2 = y0;
        y3 = y1;
        acc = (float*)d_out;           // fp32 accumulator lives in d_out
        ebuf = (uint2*)carve(EBUF);
    }
    (void)in_sizes; (void)n_in; (void)out_size;

    k_init <<<2, 256, 0, stream>>>(gcur);
    k_meta <<<NB_META, 256, 0, stream>>>(artist_w, album_w, artist_ids,
                                         album_ids, metabuf);
    k_bin1 <<<NB_BIN1, 512, 0, stream>>>(edge_src, edge_dst, edge_attr,
                                         W1, b1, W2, b2, ebuf, gcur);
    k_bin2 <<<NBUCK, 1024, 0, stream>>>(ebuf, gcur, offs, csr);
    k_deg  <<<NB_SCAN, 256, 0, stream>>>(offs, csr, dis);
    k_users<<<1024, 256, 0, stream>>>(user_w, dis, y0, acc, no_acc ? 0 : 1);
    k_items<<<NB_I, 256, 0, stream>>>(item_audio, metabuf, Wp, bp, dis,
                                      y0 + (size_t)U_CNT * 64,
                                      no_acc ? nullptr : acc + (size_t)U_CNT * 64,
                                      no_acc ? 0 : 1);
    // 4 nodes per wave -> N/4 waves -> N/16 blocks of 256
    const int PROP_BLKS = N_CNT / 16;    // 18750
    if (no_acc) {
        k_prop<<<PROP_BLKS, 256, 0, stream>>>(offs, csr, dis, y0, y1, nullptr, 0);
        k_prop<<<PROP_BLKS, 256, 0, stream>>>(offs, csr, dis, y1, y2, nullptr, 0);
        k_prop<<<PROP_BLKS, 256, 0, stream>>>(offs, csr, dis, y2, y3, nullptr, 0);
        k_final_sum<<<N_CNT / 4, 256, 0, stream>>>(y0, y1, y2, y3, (float*)d_out);
    } else {
        // y0 -> y1 -> y0 -> y1 (bf16), accumulating fp32 into acc (= d_out)
        k_prop<<<PROP_BLKS, 256, 0, stream>>>(offs, csr, dis, y0, y1, acc, 1);
        k_prop<<<PROP_BLKS, 256, 0, stream>>>(offs, csr, dis, y1, y0, acc, 1);
        k_prop<<<PROP_BLKS, 256, 0, stream>>>(offs, csr, dis, y0, y1, acc, 1);
        k_final_acc<<<N_CNT / 4, 256, 0, stream>>>(acc, (float*)d_out);
    }
}

// Round 11
// 513.156 us; speedup vs baseline: 1.0720x; 1.0720x over previous
//
#include <hip/hip_runtime.h>
#include <hip/hip_bf16.h>

#define U_CNT 200000
#define I_CNT 100000
#define N_CNT 300000
#define E_CNT 1000000
#define ATTR_D 8
#define H_DIM 32
#define NB_SCAN ((N_CNT + 255) / 256)
#define IB 128                               // items per item-block
#define NB_I ((I_CNT + IB - 1) / IB)         // 782 item blocks
#define NB_META (I_CNT / 16)                 // 6250 blocks, 16 items/block
#define XP 130                               // sXT pitch (bf16 elems)

// binning parameters
#define BSHIFT 10                            // 1024 nodes per bucket
#define NBUCK 293                            // ceil(300000/1024)
#define BCAP 12288                           // entries capacity/bucket (>20 sigma)
#define EPB 2048                             // edges per bin1 block
#define NB_BIN1 ((E_CNT + EPB - 1) / EPB)    // 489

// NOTE (rounds 1-4): all float inputs / output FLOAT32. absmax floor 1.95e-3
// == bf16 rounding of reference; threshold 1.26e-2.
// NOTE (round 7): rank-capture scatter + y-space reform. 1098 -> 951 us.
// NOTE (round 8/13/14): k_items LDS GEMM; real fix was splitting serial
// meta-gather into k_meta (4 rows/vmem instr).
// NOTE (round 9): bf16 y-storage. round 10: k_prop 4 nodes/wave (4x in-flight
// gathers) 830 -> 634. GATHERS = latency x concurrency.
// NOTE (round 11): fusion of latency-bound role with big-LDS role regressed.
// NOTE (round 12): per-thread batching regressed for ATOMICS.
// NOTE (round 15): 2-phase bucket binning CSR build. 615 -> 547, matched.
// NOTE (round 16): bin occupancy bump + prop unroll-8: net flat (550);
// k_prop now 65us at VALU 40% / 2.7TB/s — near its mixed-regime floor.
// NOTE (round 17, this round): fusion pass (producer already touches data):
// (a) k_deg fused into k_bin2 (LDS float ds_add of w during scatter ->
//     dis=rsqrt(1+sum); kills a 16MB csr re-read + launch);
// (b) k_final_sum fused into prop round 3 (k_prop_fin: y2=self in regs,
//     y3=r unrounded, only y0/y1 extra reads; out written fp32 direct);
// (c) k_init folded into k_meta block 0.

typedef unsigned short ubf;

__device__ __forceinline__ float b2f(ubf b) {
    return __uint_as_float((unsigned)b << 16);
}
__device__ __forceinline__ ubf f2b(float v) {
    unsigned u = __float_as_uint(v);
    u += 0x7fffu + ((u >> 16) & 1u);           // round to nearest even
    return (ubf)(u >> 16);
}
__device__ __forceinline__ unsigned pk2(float lo, float hi) {
    return (unsigned)f2b(lo) | ((unsigned)f2b(hi) << 16);
}
__device__ __forceinline__ float4 b4f(ushort4 u) {
    return make_float4(b2f(u.x), b2f(u.y), b2f(u.z), b2f(u.w));
}
// entry pack: x = key[0:19) | (partner&0x1FFF)<<19 ; y = partner>>13 | wb<<16
__device__ __forceinline__ uint2 packE(int key, int partner, unsigned wb) {
    return make_uint2((unsigned)key | (((unsigned)partner & 0x1FFFu) << 19),
                     ((unsigned)partner >> 13) | (wb << 16));
}

// ---------------- meta gather (+ gcur init in block 0) ----------------
__global__ void k_meta(const float* __restrict__ art, const float* __restrict__ alb,
                       const int* __restrict__ aid, const int* __restrict__ alid,
                       ubf* __restrict__ metabuf, int* __restrict__ gcur) {
    int t = threadIdx.x;
    if (blockIdx.x == 0) {
        for (int i = t; i < NBUCK; i += 256) gcur[i] = i * BCAP;
    }
    int lane = t & 63;
    int g = lane >> 4;                   // item group 0..3
    int q = lane & 15;                   // float4 slot within 256B row
    int wv = (blockIdx.x * 256 + t) >> 6;
    int it = wv * 4 + g;
    if (it >= I_CNT) return;
    int a_ = aid[it], al_ = alid[it];
    float4 va = *(const float4*)&art[(size_t)a_ * 64 + q * 4];
    float4 vb = *(const float4*)&alb[(size_t)al_ * 64 + q * 4];
    ushort4 o = make_ushort4(f2b(va.x + vb.x), f2b(va.y + vb.y),
                             f2b(va.z + vb.z), f2b(va.w + vb.w));
    *(ushort4*)&metabuf[(size_t)it * 64 + q * 4] = o;
}

// ---------------- phase 1: edge MLP + bucket binning (512 thr, 4 edges/thr) ----------------
__global__ void __launch_bounds__(512)
k_bin1(const int* __restrict__ src, const int* __restrict__ dst,
       const float* __restrict__ attr,
       const float* __restrict__ W1, const float* __restrict__ b1,
       const float* __restrict__ W2, const float* __restrict__ b2,
       uint2* __restrict__ ebuf, int* __restrict__ gcur) {
    __shared__ float sW1[ATTR_D * H_DIM];
    __shared__ float sb1[H_DIM];
    __shared__ float sW2[H_DIM];
    __shared__ float sb2;
    __shared__ int hist[NBUCK];
    __shared__ int basem[NBUCK];
    int t = threadIdx.x;
    if (t < 256) sW1[t] = W1[t];
    if (t < H_DIM) { sb1[t] = b1[t]; sW2[t] = W2[t]; }
    if (t == 0) sb2 = b2[0];
    for (int i = t; i < NBUCK; i += 512) hist[i] = 0;
    __syncthreads();
    int ebase = blockIdx.x * EPB;
    int sarr[4], darr[4];
    unsigned warr[4];
    #pragma unroll
    for (int k = 0; k < 4; ++k) {
        int e = ebase + k * 512 + t;
        sarr[k] = -1;
        if (e < E_CNT) {
            const float4* a4 = (const float4*)attr + (size_t)e * 2;
            float4 r0 = a4[0];
            float4 r1 = a4[1];
            float a[8] = {r0.x, r0.y, r0.z, r0.w, r1.x, r1.y, r1.z, r1.w};
            float z = sb2;
            #pragma unroll
            for (int h = 0; h < H_DIM; ++h) {
                float acc = sb1[h];
                #pragma unroll
                for (int kk = 0; kk < 8; ++kk) acc = fmaf(a[kk], sW1[kk * H_DIM + h], acc);
                acc = fmaxf(acc, 0.0f);
                z = fmaf(acc, sW2[h], z);
            }
            float w = 1.0f / (1.0f + __expf(-z));
            w = fmaxf(w, 1e-6f);
            int s = src[e], d = U_CNT + dst[e];
            sarr[k] = s; darr[k] = d; warr[k] = (unsigned)f2b(w);
            atomicAdd(&hist[s >> BSHIFT], 1);
            atomicAdd(&hist[d >> BSHIFT], 1);
        }
    }
    __syncthreads();
    for (int i = t; i < NBUCK; i += 512) {
        int h = hist[i];
        basem[i] = (h > 0) ? atomicAdd(&gcur[i], h) : 0;
    }
    __syncthreads();
    for (int i = t; i < NBUCK; i += 512) hist[i] = 0;   // reuse as cursor
    __syncthreads();
    #pragma unroll
    for (int k = 0; k < 4; ++k) {
        if (sarr[k] >= 0) {
            int s = sarr[k], d = darr[k];
            unsigned wb = warr[k];
            int bs = s >> BSHIFT;
            int r = atomicAdd(&hist[bs], 1);
            ebuf[(size_t)basem[bs] + r] = packE(s, d, wb);
            int bd = d >> BSHIFT;
            r = atomicAdd(&hist[bd], 1);
            ebuf[(size_t)basem[bd] + r] = packE(d, s, wb);
        }
    }
}

// ---------------- phase 2: per-bucket CSR build + fused deg/dis ----------------
__global__ void __launch_bounds__(1024)
k_bin2(const uint2* __restrict__ ebuf, const int* __restrict__ gcur,
       int* __restrict__ offs, int2* __restrict__ csr,
       float* __restrict__ dis) {
    __shared__ int ldsCnt[NBUCK];
    __shared__ int ldsH[1024];
    __shared__ int ldsC[1024];
    __shared__ int ldsT[1024];
    __shared__ float ldsW[1024];
    __shared__ int sMeta[2];          // csr_base, mycount
    int t = threadIdx.x;
    int b = blockIdx.x;
    if (t < NBUCK) ldsCnt[t] = gcur[t] - t * BCAP;
    ldsH[t] = 0;
    ldsC[t] = 0;
    ldsW[t] = 0.0f;
    __syncthreads();
    if (t == 0) {
        int base = 0;
        for (int i = 0; i < b; ++i) base += ldsCnt[i];
        sMeta[0] = base;
        sMeta[1] = ldsCnt[b];
    }
    __syncthreads();
    int csr_base = sMeta[0], mycount = sMeta[1];
    size_t eb = (size_t)b * BCAP;
    int first = b << BSHIFT;
    // node histogram
    for (int i = t; i < mycount; i += 1024) {
        uint2 en = ebuf[eb + i];
        atomicAdd(&ldsH[(en.x & 0x7FFFFu) - first], 1);
    }
    __syncthreads();
    // exclusive scan of 1024 counters (Hillis-Steele)
    int v0 = ldsH[t];
    ldsT[t] = v0;
    __syncthreads();
    #pragma unroll
    for (int off = 1; off < 1024; off <<= 1) {
        int x = (t >= off) ? ldsT[t - off] : 0;
        __syncthreads();
        ldsT[t] += x;
        __syncthreads();
    }
    int excl = ldsT[t] - v0;
    ldsH[t] = excl;                   // ldsH now exclusive offsets
    __syncthreads();
    int ncnt = min(1024, N_CNT - first);
    if (t < ncnt) offs[first + t] = csr_base + ldsH[t];
    if (b == NBUCK - 1 && t == 0) offs[N_CNT] = 2 * E_CNT;
    // scatter entries to final CSR (L2-local span) + accumulate deg in LDS
    for (int i = t; i < mycount; i += 1024) {
        uint2 en = ebuf[eb + i];
        int key = (int)(en.x & 0x7FFFFu);
        int partner = (int)((en.x >> 19) | ((en.y & 0xFFFFu) << 13));
        unsigned wb = en.y >> 16;
        int li = key - first;
        int r = atomicAdd(&ldsC[li], 1);
        csr[csr_base + ldsH[li] + r] = make_int2(partner, (int)(wb << 16));
        atomicAdd(&ldsW[li], b2f((ubf)wb));
    }
    __syncthreads();
    if (t < ncnt) dis[first + t] = rsqrtf(1.0f + ldsW[t]);   // self loop = 1
}

// ---------------- users: y0 = dis * l2norm(user_w) ----------------
__global__ void k_users(const float* __restrict__ user_w, const float* __restrict__ dis,
                        ubf* __restrict__ y0, float* __restrict__ acc, int use_acc) {
    int lane = threadIdx.x & 63;
    int wv = (blockIdx.x * blockDim.x + threadIdx.x) >> 6;
    int nw = (gridDim.x * blockDim.x) >> 6;
    for (int r = wv; r < U_CNT; r += nw) {
        int idx = r * 64 + lane;
        float v = user_w[idx];
        float ss = v * v;
        #pragma unroll
        for (int m = 32; m >= 1; m >>= 1) ss += __shfl_xor(ss, m, 64);
        float inv = dis[r] / fmaxf(sqrtf(ss), 1e-12f);
        float o = v * inv;
        y0[idx] = f2b(o);
        if (use_acc) acc[idx] = o;
    }
}

// ---------------- items: pure-streaming bf16-LDS GEMM, 4 items x 8 outs ----------------
__global__ void __launch_bounds__(256)
k_items(const float* __restrict__ audio, const ubf* __restrict__ metabuf,
        const float* __restrict__ Wp, const float* __restrict__ bp,
        const float* __restrict__ dis,
        ubf* __restrict__ yitem, float* __restrict__ accitem, int use_acc) {
    __shared__ __align__(16) ubf sXT[128 * XP];
    __shared__ __align__(16) ubf sW[128 * 64];
    int t = threadIdx.x;
    int base = blockIdx.x * IB;
    // stage Wp -> bf16
    {
        const float4* wg = (const float4*)Wp;
        #pragma unroll
        for (int r = 0; r < 8; ++r) {
            int idx = r * 256 + t;
            float4 v = wg[idx];
            ushort4 o = make_ushort4(f2b(v.x), f2b(v.y), f2b(v.z), f2b(v.w));
            *(ushort4*)&sW[idx * 4] = o;
        }
    }
    // stage audio -> sXT[f][i] transposed
    {
        const float4* g = (const float4*)audio + (size_t)base * 16;
        #pragma unroll
        for (int r = 0; r < 8; ++r) {
            int idx = r * 256 + t;               // 0..2047
            int i = idx >> 4, fq = idx & 15;
            float4 v = make_float4(0.f, 0.f, 0.f, 0.f);
            if (base + i < I_CNT) v = g[idx];
            sXT[(4 * fq + 0) * XP + i] = f2b(v.x);
            sXT[(4 * fq + 1) * XP + i] = f2b(v.y);
            sXT[(4 * fq + 2) * XP + i] = f2b(v.z);
            sXT[(4 * fq + 3) * XP + i] = f2b(v.w);
        }
    }
    // stage metabuf -> sXT[64+f][i]
    {
        const uint4* m4 = (const uint4*)(metabuf + (size_t)base * 64);
        #pragma unroll
        for (int r = 0; r < 4; ++r) {
            int idx = r * 256 + t;               // 0..1023
            int i = idx >> 3, c = idx & 7;
            uint4 m = make_uint4(0u, 0u, 0u, 0u);
            if (base + i < I_CNT) m = m4[idx];
            ubf* dp = &sXT[(64 + 8 * c) * XP + i];
            dp[0 * XP] = (ubf)(m.x & 0xffffu); dp[1 * XP] = (ubf)(m.x >> 16);
            dp[2 * XP] = (ubf)(m.y & 0xffffu); dp[3 * XP] = (ubf)(m.y >> 16);
            dp[4 * XP] = (ubf)(m.z & 0xffffu); dp[5 * XP] = (ubf)(m.z >> 16);
            dp[6 * XP] = (ubf)(m.w & 0xffffu); dp[7 * XP] = (ubf)(m.w >> 16);
        }
    }
    __syncthreads();
    int og = t & 7;                      // outs 8og..8og+7
    int igr = t >> 3;                    // items 4igr..4igr+3
    float c[4][8];
    {
        float bv[8];
        #pragma unroll
        for (int j = 0; j < 8; ++j) bv[j] = bp[8 * og + j];
        #pragma unroll
        for (int i = 0; i < 4; ++i)
            #pragma unroll
            for (int j = 0; j < 8; ++j) c[i][j] = bv[j];
    }
    const ubf* xcol = &sXT[4 * igr];
    const ubf* wrow = &sW[8 * og];
    #pragma unroll 2
    for (int k = 0; k < 128; ++k) {
        ushort4 xu = *(const ushort4*)&xcol[k * XP];
        uint4 wu = *(const uint4*)&wrow[k * 64];
        float x[4] = {b2f(xu.x), b2f(xu.y), b2f(xu.z), b2f(xu.w)};
        float w[8];
        w[0] = __uint_as_float(wu.x << 16); w[1] = __uint_as_float(wu.x & 0xffff0000u);
        w[2] = __uint_as_float(wu.y << 16); w[3] = __uint_as_float(wu.y & 0xffff0000u);
        w[4] = __uint_as_float(wu.z << 16); w[5] = __uint_as_float(wu.z & 0xffff0000u);
        w[6] = __uint_as_float(wu.w << 16); w[7] = __uint_as_float(wu.w & 0xffff0000u);
        #pragma unroll
        for (int i = 0; i < 4; ++i)
            #pragma unroll
            for (int j = 0; j < 8; ++j) c[i][j] = fmaf(x[i], w[j], c[i][j]);
    }
    #pragma unroll
    for (int i = 0; i < 4; ++i) {
        float ss = 0.f;
        #pragma unroll
        for (int j = 0; j < 8; ++j) ss += c[i][j] * c[i][j];
        ss += __shfl_xor(ss, 1, 64);
        ss += __shfl_xor(ss, 2, 64);
        ss += __shfl_xor(ss, 4, 64);
        int it = base + 4 * igr + i;
        if (it < I_CNT) {
            float q = dis[U_CNT + it] / fmaxf(sqrtf(ss), 1e-12f);
            uint4 o;
            o.x = pk2(c[i][0] * q, c[i][1] * q);
            o.y = pk2(c[i][2] * q, c[i][3] * q);
            o.z = pk2(c[i][4] * q, c[i][5] * q);
            o.w = pk2(c[i][6] * q, c[i][7] * q);
            *(uint4*)&yitem[(size_t)it * 64 + 8 * og] = o;
            if (use_acc) {
                float4* ap = (float4*)&accitem[(size_t)it * 64 + 8 * og];
                ap[0] = make_float4(c[i][0] * q, c[i][1] * q, c[i][2] * q, c[i][3] * q);
                ap[1] = make_float4(c[i][4] * q, c[i][5] * q, c[i][6] * q, c[i][7] * q);
            }
        }
    }
}

// ---------------- shared gather core for one LGConv round ----------------
__device__ __forceinline__ void prop_gather(const int* offs, const int2* csr,
                                            const ubf* yin, int c, int s4,
                                            float4& a0, float4& a1,
                                            float4& a2, float4& a3) {
    int e = offs[c], end = offs[c + 1];
    for (; e + 7 < end; e += 8) {
        int2 e0 = csr[e], e1 = csr[e + 1], e2 = csr[e + 2], e3 = csr[e + 3];
        int2 e4 = csr[e + 4], e5 = csr[e + 5], e6 = csr[e + 6], e7 = csr[e + 7];
        ushort4 g0 = *(const ushort4*)&yin[(size_t)e0.x * 64 + s4];
        ushort4 g1 = *(const ushort4*)&yin[(size_t)e1.x * 64 + s4];
        ushort4 g2 = *(const ushort4*)&yin[(size_t)e2.x * 64 + s4];
        ushort4 g3 = *(const ushort4*)&yin[(size_t)e3.x * 64 + s4];
        ushort4 g4 = *(const ushort4*)&yin[(size_t)e4.x * 64 + s4];
        ushort4 g5 = *(const ushort4*)&yin[(size_t)e5.x * 64 + s4];
        ushort4 g6 = *(const ushort4*)&yin[(size_t)e6.x * 64 + s4];
        ushort4 g7 = *(const ushort4*)&yin[(size_t)e7.x * 64 + s4];
        float w0 = __int_as_float(e0.y), w1 = __int_as_float(e1.y);
        float w2 = __int_as_float(e2.y), w3 = __int_as_float(e3.y);
        float w4 = __int_as_float(e4.y), w5 = __int_as_float(e5.y);
        float w6 = __int_as_float(e6.y), w7 = __int_as_float(e7.y);
        float4 f0 = b4f(g0), f1 = b4f(g1), f2 = b4f(g2), f3 = b4f(g3);
        float4 f4 = b4f(g4), f5 = b4f(g5), f6 = b4f(g6), f7 = b4f(g7);
        a0.x = fmaf(w0, f0.x, a0.x); a0.y = fmaf(w0, f0.y, a0.y);
        a0.z = fmaf(w0, f0.z, a0.z); a0.w = fmaf(w0, f0.w, a0.w);
        a1.x = fmaf(w1, f1.x, a1.x); a1.y = fmaf(w1, f1.y, a1.y);
        a1.z = fmaf(w1, f1.z, a1.z); a1.w = fmaf(w1, f1.w, a1.w);
        a2.x = fmaf(w2, f2.x, a2.x); a2.y = fmaf(w2, f2.y, a2.y);
        a2.z = fmaf(w2, f2.z, a2.z); a2.w = fmaf(w2, f2.w, a2.w);
        a3.x = fmaf(w3, f3.x, a3.x); a3.y = fmaf(w3, f3.y, a3.y);
        a3.z = fmaf(w3, f3.z, a3.z); a3.w = fmaf(w3, f3.w, a3.w);
        a0.x = fmaf(w4, f4.x, a0.x); a0.y = fmaf(w4, f4.y, a0.y);
        a0.z = fmaf(w4, f4.z, a0.z); a0.w = fmaf(w4, f4.w, a0.w);
        a1.x = fmaf(w5, f5.x, a1.x); a1.y = fmaf(w5, f5.y, a1.y);
        a1.z = fmaf(w5, f5.z, a1.z); a1.w = fmaf(w5, f5.w, a1.w);
        a2.x = fmaf(w6, f6.x, a2.x); a2.y = fmaf(w6, f6.y, a2.y);
        a2.z = fmaf(w6, f6.z, a2.z); a2.w = fmaf(w6, f6.w, a2.w);
        a3.x = fmaf(w7, f7.x, a3.x); a3.y = fmaf(w7, f7.y, a3.y);
        a3.z = fmaf(w7, f7.z, a3.z); a3.w = fmaf(w7, f7.w, a3.w);
    }
    for (; e + 3 < end; e += 4) {
        int2 e0 = csr[e], e1 = csr[e + 1], e2 = csr[e + 2], e3 = csr[e + 3];
        ushort4 g0 = *(const ushort4*)&yin[(size_t)e0.x * 64 + s4];
        ushort4 g1 = *(const ushort4*)&yin[(size_t)e1.x * 64 + s4];
        ushort4 g2 = *(const ushort4*)&yin[(size_t)e2.x * 64 + s4];
        ushort4 g3 = *(const ushort4*)&yin[(size_t)e3.x * 64 + s4];
        float w0 = __int_as_float(e0.y), w1 = __int_as_float(e1.y);
        float w2 = __int_as_float(e2.y), w3 = __int_as_float(e3.y);
        float4 f0 = b4f(g0), f1 = b4f(g1), f2 = b4f(g2), f3 = b4f(g3);
        a0.x = fmaf(w0, f0.x, a0.x); a0.y = fmaf(w0, f0.y, a0.y);
        a0.z = fmaf(w0, f0.z, a0.z); a0.w = fmaf(w0, f0.w, a0.w);
        a1.x = fmaf(w1, f1.x, a1.x); a1.y = fmaf(w1, f1.y, a1.y);
        a1.z = fmaf(w1, f1.z, a1.z); a1.w = fmaf(w1, f1.w, a1.w);
        a2.x = fmaf(w2, f2.x, a2.x); a2.y = fmaf(w2, f2.y, a2.y);
        a2.z = fmaf(w2, f2.z, a2.z); a2.w = fmaf(w2, f2.w, a2.w);
        a3.x = fmaf(w3, f3.x, a3.x); a3.y = fmaf(w3, f3.y, a3.y);
        a3.z = fmaf(w3, f3.z, a3.z); a3.w = fmaf(w3, f3.w, a3.w);
    }
    for (; e < end; ++e) {
        int2 ee = csr[e];
        ushort4 gg = *(const ushort4*)&yin[(size_t)ee.x * 64 + s4];
        float ww = __int_as_float(ee.y);
        float4 ff = b4f(gg);
        a0.x = fmaf(ww, ff.x, a0.x); a0.y = fmaf(ww, ff.y, a0.y);
        a0.z = fmaf(ww, ff.z, a0.z); a0.w = fmaf(ww, ff.w, a0.w);
    }
}

// ---------------- LGConv round: 4 nodes/wave, 16 lanes/node ----------------
__global__ void k_prop(const int* __restrict__ offs, const int2* __restrict__ csr,
                       const float* __restrict__ dis,
                       const ubf* __restrict__ yin, ubf* __restrict__ yout,
                       float* __restrict__ acc, int use_acc) {
    int lane = threadIdx.x & 63;
    int g = lane >> 4;
    int s4 = (lane & 15) * 4;
    int wv = (blockIdx.x * 256 + threadIdx.x) >> 6;
    int c = wv * 4 + g;
    if (c >= N_CNT) return;
    float dc = dis[c];
    float4 a0 = make_float4(0.f, 0.f, 0.f, 0.f);
    float4 a1 = a0, a2 = a0, a3 = a0;
    prop_gather(offs, csr, yin, c, s4, a0, a1, a2, a3);
    size_t idx = (size_t)c * 64 + s4;
    float4 self = b4f(*(const ushort4*)&yin[idx]);
    float dc2 = dc * dc;
    float4 r;
    r.x = dc2 * (((a0.x + a1.x) + (a2.x + a3.x)) + self.x);
    r.y = dc2 * (((a0.y + a1.y) + (a2.y + a3.y)) + self.y);
    r.z = dc2 * (((a0.z + a1.z) + (a2.z + a3.z)) + self.z);
    r.w = dc2 * (((a0.w + a1.w) + (a2.w + a3.w)) + self.w);
    *(ushort4*)&yout[idx] = make_ushort4(f2b(r.x), f2b(r.y), f2b(r.z), f2b(r.w));
    if (use_acc) {
        float4* ap = (float4*)&acc[idx];
        float4 av = *ap;
        av.x += r.x; av.y += r.y; av.z += r.z; av.w += r.w;
        *ap = av;
    }
}

// ---------------- final round fused with layer-sum + l2norm epilogue ----------------
// yin = y2 (self); v = y0 + y1 + y2 + y3 where y3 = r (unrounded);
// out = v / max(||v||, eps)  (16-lane group holds the node's 64 dims)
__global__ void k_prop_fin(const int* __restrict__ offs, const int2* __restrict__ csr,
                           const float* __restrict__ dis,
                           const ubf* __restrict__ y0, const ubf* __restrict__ y1,
                           const ubf* __restrict__ yin, float* __restrict__ out) {
    int lane = threadIdx.x & 63;
    int g = lane >> 4;
    int s4 = (lane & 15) * 4;
    int wv = (blockIdx.x * 256 + threadIdx.x) >> 6;
    int c = wv * 4 + g;
    if (c >= N_CNT) return;
    float dc = dis[c];
    float4 a0 = make_float4(0.f, 0.f, 0.f, 0.f);
    float4 a1 = a0, a2 = a0, a3 = a0;
    prop_gather(offs, csr, yin, c, s4, a0, a1, a2, a3);
    size_t idx = (size_t)c * 64 + s4;
    float4 self = b4f(*(const ushort4*)&yin[idx]);
    float dc2 = dc * dc;
    float4 r;
    r.x = dc2 * (((a0.x + a1.x) + (a2.x + a3.x)) + self.x);
    r.y = dc2 * (((a0.y + a1.y) + (a2.y + a3.y)) + self.y);
    r.z = dc2 * (((a0.z + a1.z) + (a2.z + a3.z)) + self.z);
    r.w = dc2 * (((a0.w + a1.w) + (a2.w + a3.w)) + self.w);
    float4 v0 = b4f(*(const ushort4*)&y0[idx]);
    float4 v1 = b4f(*(const ushort4*)&y1[idx]);
    float4 v;
    v.x = (v0.x + v1.x) + (self.x + r.x);
    v.y = (v0.y + v1.y) + (self.y + r.y);
    v.z = (v0.z + v1.z) + (self.z + r.z);
    v.w = (v0.w + v1.w) + (self.w + r.w);
    float ss = v.x * v.x + v.y * v.y + v.z * v.z + v.w * v.w;
    ss += __shfl_xor(ss, 1, 64);
    ss += __shfl_xor(ss, 2, 64);
    ss += __shfl_xor(ss, 4, 64);
    ss += __shfl_xor(ss, 8, 64);
    float inv = 1.0f / fmaxf(sqrtf(ss), 1e-12f);
    *(float4*)&out[idx] = make_float4(v.x * inv, v.y * inv, v.z * inv, v.w * inv);
}

// ---------------- epilogue A: l2norm(acc)  (acc fp32, may alias out) ----------------
__global__ void k_final_acc(const float* __restrict__ acc, float* __restrict__ out) {
    int lane = threadIdx.x & 63;
    int c = (blockIdx.x * 256 + threadIdx.x) >> 6;
    if (c >= N_CNT) return;
    int idx = c * 64 + lane;
    float v = acc[idx];
    float ss = v * v;
    #pragma unroll
    for (int m = 32; m >= 1; m >>= 1) ss += __shfl_xor(ss, m, 64);
    out[idx] = v / fmaxf(sqrtf(ss), 1e-12f);
}

extern "C" void kernel_launch(void* const* d_in, const int* in_sizes, int n_in,
                              void* d_out, int out_size, void* d_ws, size_t ws_size,
                              hipStream_t stream) {
    const int*   edge_src   = (const int*)  d_in[0];
    const int*   edge_dst   = (const int*)  d_in[1];
    const float* edge_attr  = (const float*)d_in[2];
    const float* user_w     = (const float*)d_in[3];
    const float* artist_w   = (const float*)d_in[4];
    const float* album_w    = (const float*)d_in[5];
    const float* item_audio = (const float*)d_in[6];
    const int*   artist_ids = (const int*)  d_in[7];
    const int*   album_ids  = (const int*)  d_in[8];
    const float* Wp         = (const float*)d_in[9];
    const float* bp         = (const float*)d_in[10];
    const float* W1         = (const float*)d_in[11];
    const float* b1         = (const float*)d_in[12];
    const float* W2         = (const float*)d_in[13];
    const float* b2         = (const float*)d_in[14];

    char* p = (char*)d_ws;
    auto carve = [&](size_t bytes) -> void* {
        void* q = (void*)p;
        p += (bytes + 255) & ~(size_t)255;
        return q;
    };
    // common carve (~31 MB)
    float* dis    = (float*)carve((size_t)N_CNT * 4);
    int*   offs   = (int*)  carve((size_t)(N_CNT + 1) * 4);
    int*   gcur   = (int*)  carve((size_t)NBUCK * 4);
    int2*  csr    = (int2*) carve((size_t)2 * E_CNT * 8);
    ubf*   metabuf= (ubf*)  carve((size_t)I_CNT * 64 * 2);  // 12.8 MB bf16
    const size_t YB = (size_t)N_CNT * 64 * 2;      // 38.4 MB per bf16 y buffer
    const size_t EBUF = (size_t)NBUCK * BCAP * 8;  // 28.8 MB entry buffer
    size_t used = (size_t)(p - (char*)d_ws);
    // Path B (no acc RMW) needs y0,y1,y2 bf16 in ws; ebuf aliases y2 (dead
    // until prop round 2). Else ping-pong + fp32 acc in d_out.
    int no_acc = (ws_size >= used + 3 * YB + (size_t)4096) ? 1 : 0;
    ubf *y0, *y1, *y2;
    uint2* ebuf;
    float* acc = nullptr;
    if (no_acc) {
        y0 = (ubf*)carve(YB);
        y1 = (ubf*)carve(YB);
        y2 = (ubf*)carve(YB);
        ebuf = (uint2*)y2;             // alias: 38.4MB >= 28.8MB
    } else {
        y0 = (ubf*)carve(YB);
        y1 = (ubf*)carve(YB);
        y2 = y0;
        acc = (float*)d_out;           // fp32 accumulator lives in d_out
        ebuf = (uint2*)carve(EBUF);
    }
    (void)in_sizes; (void)n_in; (void)out_size;

    k_meta <<<NB_META, 256, 0, stream>>>(artist_w, album_w, artist_ids,
                                         album_ids, metabuf, gcur);
    k_bin1 <<<NB_BIN1, 512, 0, stream>>>(edge_src, edge_dst, edge_attr,
                                         W1, b1, W2, b2, ebuf, gcur);
    k_bin2 <<<NBUCK, 1024, 0, stream>>>(ebuf, gcur, offs, csr, dis);
    k_users<<<1024, 256, 0, stream>>>(user_w, dis, y0, acc, no_acc ? 0 : 1);
    k_items<<<NB_I, 256, 0, stream>>>(item_audio, metabuf, Wp, bp, dis,
                                      y0 + (size_t)U_CNT * 64,
                                      no_acc ? nullptr : acc + (size_t)U_CNT * 64,
                                      no_acc ? 0 : 1);
    // 4 nodes per wave -> N/4 waves -> N/16 blocks of 256
    const int PROP_BLKS = N_CNT / 16;    // 18750
    if (no_acc) {
        k_prop<<<PROP_BLKS, 256, 0, stream>>>(offs, csr, dis, y0, y1, nullptr, 0);
        k_prop<<<PROP_BLKS, 256, 0, stream>>>(offs, csr, dis, y1, y2, nullptr, 0);
        k_prop_fin<<<PROP_BLKS, 256, 0, stream>>>(offs, csr, dis, y0, y1, y2,
                                                  (float*)d_out);
    } else {
        // y0 -> y1 -> y0 -> y1 (bf16), accumulating fp32 into acc (= d_out)
        k_prop<<<PROP_BLKS, 256, 0, stream>>>(offs, csr, dis, y0, y1, acc, 1);
        k_prop<<<PROP_BLKS, 256, 0, stream>>>(offs, csr, dis, y1, y0, acc, 1);
        k_prop<<<PROP_BLKS, 256, 0, stream>>>(offs, csr, dis, y0, y1, acc, 1);
        k_final_acc<<<N_CNT / 4, 256, 0, stream>>>(acc, (float*)d_out);
    }
}

// Round 12
// 499.411 us; speedup vs baseline: 1.1015x; 1.0275x over previous
//
#include <hip/hip_runtime.h>
#include <hip/hip_bf16.h>

#define U_CNT 200000
#define I_CNT 100000
#define N_CNT 300000
#define E_CNT 1000000
#define ATTR_D 8
#define H_DIM 32
#define IB 128                               // items per item-block
#define NB_I ((I_CNT + IB - 1) / IB)         // 782 item blocks
#define XP 130                               // sXT pitch (bf16 elems)

// binning parameters
#define BSHIFT 10                            // 1024 nodes per bucket
#define NBUCK 293                            // ceil(300000/1024)
#define BCAP 12288                           // entries capacity/bucket (>20 sigma)
#define EPB 2048                             // edges per bin1 block
#define NB_BIN1 ((E_CNT + EPB - 1) / EPB)    // 489
#define NB_META5 (I_CNT / 32)                // 3125 meta-role blocks (512 thr)

// NOTE (rounds 1-4): all float inputs / output FLOAT32. absmax floor 1.95e-3
// == bf16 rounding of reference; threshold 1.26e-2.
// NOTE (round 7): rank-capture scatter + y-space reform. 1098 -> 951 us.
// NOTE (round 8/13/14): k_items LDS GEMM; real fix was splitting serial
// meta-gather into k_meta (4 rows/vmem instr).
// NOTE (round 9): bf16 y-storage. round 10: k_prop 4 nodes/wave. GATHERS =
// latency x concurrency (in-flight rows per wave is the lever).
// NOTE (round 11): fusing latency-bound role with BIG-LDS role regressed.
// NOTE (round 12): per-thread batching regressed for ATOMICS.
// NOTE (round 15): 2-phase bucket binning CSR build. 615 -> 547.
// NOTE (round 17): fusion pass (deg->bin2, final_sum->prop_fin). 550 -> 513.
// NOTE (round 18, this round): (a) k_prop family -> 8 nodes/wave, 8 lanes/
// node, uint4/lane: one gather instr = 8 rows (2x in-flight entries; user
// nodes deg~5 were concurrency-starved at 4 rows/instr). (b) k_meta fused
// into k_bin1 as block-range role (both latency-bound, both small-LDS —
// inverse of round-11's failure); gcur is delta-based (memset 0).
// (c) k_bin2 scan: Hillis-Steele (20 barriers) -> wave shfl scan (2).

typedef unsigned short ubf;

__device__ __forceinline__ float b2f(ubf b) {
    return __uint_as_float((unsigned)b << 16);
}
__device__ __forceinline__ ubf f2b(float v) {
    unsigned u = __float_as_uint(v);
    u += 0x7fffu + ((u >> 16) & 1u);           // round to nearest even
    return (ubf)(u >> 16);
}
__device__ __forceinline__ unsigned pk2(float lo, float hi) {
    return (unsigned)f2b(lo) | ((unsigned)f2b(hi) << 16);
}
// unpack 8 bf16 (uint4) -> 8 f32
__device__ __forceinline__ void unpack8(uint4 g, float f[8]) {
    f[0] = __uint_as_float(g.x << 16); f[1] = __uint_as_float(g.x & 0xffff0000u);
    f[2] = __uint_as_float(g.y << 16); f[3] = __uint_as_float(g.y & 0xffff0000u);
    f[4] = __uint_as_float(g.z << 16); f[5] = __uint_as_float(g.z & 0xffff0000u);
    f[6] = __uint_as_float(g.w << 16); f[7] = __uint_as_float(g.w & 0xffff0000u);
}
// entry pack: x = key[0:19) | (partner&0x1FFF)<<19 ; y = partner>>13 | wb<<16
__device__ __forceinline__ uint2 packE(int key, int partner, unsigned wb) {
    return make_uint2((unsigned)key | (((unsigned)partner & 0x1FFFu) << 19),
                     ((unsigned)partner >> 13) | (wb << 16));
}

// ---------------- phase 1: edge MLP + binning | meta-gather role ----------------
__global__ void __launch_bounds__(512)
k_bin1(const int* __restrict__ src, const int* __restrict__ dst,
       const float* __restrict__ attr,
       const float* __restrict__ W1, const float* __restrict__ b1,
       const float* __restrict__ W2, const float* __restrict__ b2,
       uint2* __restrict__ ebuf, int* __restrict__ gcur,
       const float* __restrict__ art, const float* __restrict__ alb,
       const int* __restrict__ aid, const int* __restrict__ alid,
       ubf* __restrict__ metabuf) {
    __shared__ float sW1[ATTR_D * H_DIM];
    __shared__ float sb1[H_DIM];
    __shared__ float sW2[H_DIM];
    __shared__ float sb2;
    __shared__ int hist[NBUCK];
    __shared__ int basem[NBUCK];
    int t = threadIdx.x;
    int bx = blockIdx.x;
    if (bx >= NB_BIN1) {
        // -------- meta role: 4 items/wave, 16 lanes/item, float4/lane --------
        int lane = t & 63;
        int g = lane >> 4;
        int q = lane & 15;
        int wv = ((bx - NB_BIN1) * 512 + t) >> 6;
        int it = wv * 4 + g;                 // exact: NB_META5*8 waves * 4 = I_CNT
        if (it >= I_CNT) return;
        int a_ = aid[it], al_ = alid[it];
        float4 va = *(const float4*)&art[(size_t)a_ * 64 + q * 4];
        float4 vb = *(const float4*)&alb[(size_t)al_ * 64 + q * 4];
        ushort4 o = make_ushort4(f2b(va.x + vb.x), f2b(va.y + vb.y),
                                 f2b(va.z + vb.z), f2b(va.w + vb.w));
        *(ushort4*)&metabuf[(size_t)it * 64 + q * 4] = o;
        return;
    }
    // -------- bin1 role --------
    if (t < 256) sW1[t] = W1[t];
    if (t < H_DIM) { sb1[t] = b1[t]; sW2[t] = W2[t]; }
    if (t == 0) sb2 = b2[0];
    for (int i = t; i < NBUCK; i += 512) hist[i] = 0;
    __syncthreads();
    int ebase = bx * EPB;
    int sarr[4], darr[4];
    unsigned warr[4];
    #pragma unroll
    for (int k = 0; k < 4; ++k) {
        int e = ebase + k * 512 + t;
        sarr[k] = -1;
        if (e < E_CNT) {
            const float4* a4 = (const float4*)attr + (size_t)e * 2;
            float4 r0 = a4[0];
            float4 r1 = a4[1];
            float a[8] = {r0.x, r0.y, r0.z, r0.w, r1.x, r1.y, r1.z, r1.w};
            float z = sb2;
            #pragma unroll
            for (int h = 0; h < H_DIM; ++h) {
                float acc = sb1[h];
                #pragma unroll
                for (int kk = 0; kk < 8; ++kk) acc = fmaf(a[kk], sW1[kk * H_DIM + h], acc);
                acc = fmaxf(acc, 0.0f);
                z = fmaf(acc, sW2[h], z);
            }
            float w = 1.0f / (1.0f + __expf(-z));
            w = fmaxf(w, 1e-6f);
            int s = src[e], d = U_CNT + dst[e];
            sarr[k] = s; darr[k] = d; warr[k] = (unsigned)f2b(w);
            atomicAdd(&hist[s >> BSHIFT], 1);
            atomicAdd(&hist[d >> BSHIFT], 1);
        }
    }
    __syncthreads();
    for (int i = t; i < NBUCK; i += 512) {
        int h = hist[i];
        basem[i] = (h > 0) ? (i * BCAP + atomicAdd(&gcur[i], h)) : 0;
    }
    __syncthreads();
    for (int i = t; i < NBUCK; i += 512) hist[i] = 0;   // reuse as cursor
    __syncthreads();
    #pragma unroll
    for (int k = 0; k < 4; ++k) {
        if (sarr[k] >= 0) {
            int s = sarr[k], d = darr[k];
            unsigned wb = warr[k];
            int bs = s >> BSHIFT;
            int r = atomicAdd(&hist[bs], 1);
            ebuf[(size_t)basem[bs] + r] = packE(s, d, wb);
            int bd = d >> BSHIFT;
            r = atomicAdd(&hist[bd], 1);
            ebuf[(size_t)basem[bd] + r] = packE(d, s, wb);
        }
    }
}

// ---------------- phase 2: per-bucket CSR build + fused deg/dis ----------------
__global__ void __launch_bounds__(1024)
k_bin2(const uint2* __restrict__ ebuf, const int* __restrict__ gcur,
       int* __restrict__ offs, int2* __restrict__ csr,
       float* __restrict__ dis) {
    __shared__ int ldsCnt[NBUCK];
    __shared__ int ldsH[1024];
    __shared__ int ldsC[1024];
    __shared__ float ldsW[1024];
    __shared__ int ldsT[16];
    __shared__ int sMeta[2];          // csr_base, mycount
    int t = threadIdx.x;
    int b = blockIdx.x;
    if (t < NBUCK) ldsCnt[t] = gcur[t];   // gcur is delta-based: == count
    ldsH[t] = 0;
    ldsC[t] = 0;
    ldsW[t] = 0.0f;
    __syncthreads();
    if (t == 0) {
        int base = 0;
        for (int i = 0; i < b; ++i) base += ldsCnt[i];
        sMeta[0] = base;
        sMeta[1] = ldsCnt[b];
    }
    __syncthreads();
    int csr_base = sMeta[0], mycount = sMeta[1];
    size_t eb = (size_t)b * BCAP;
    int first = b << BSHIFT;
    // node histogram
    for (int i = t; i < mycount; i += 1024) {
        uint2 en = ebuf[eb + i];
        atomicAdd(&ldsH[(en.x & 0x7FFFFu) - first], 1);
    }
    __syncthreads();
    // exclusive scan of 1024 counters: wave shfl scan + 16 wave-sums
    int v0 = ldsH[t];
    int incl = v0;
    #pragma unroll
    for (int off = 1; off < 64; off <<= 1) {
        int x = __shfl_up(incl, off, 64);
        if ((t & 63) >= off) incl += x;
    }
    int w = t >> 6;
    if ((t & 63) == 63) ldsT[w] = incl;
    __syncthreads();
    if (t == 0) {
        int run = 0;
        #pragma unroll
        for (int i = 0; i < 16; ++i) { int x = ldsT[i]; ldsT[i] = run; run += x; }
    }
    __syncthreads();
    int excl = ldsT[w] + incl - v0;
    ldsH[t] = excl;                   // ldsH now exclusive offsets
    __syncthreads();
    int ncnt = min(1024, N_CNT - first);
    if (t < ncnt) offs[first + t] = csr_base + ldsH[t];
    if (b == NBUCK - 1 && t == 0) offs[N_CNT] = 2 * E_CNT;
    // scatter entries to final CSR (L2-local span) + accumulate deg in LDS
    for (int i = t; i < mycount; i += 1024) {
        uint2 en = ebuf[eb + i];
        int key = (int)(en.x & 0x7FFFFu);
        int partner = (int)((en.x >> 19) | ((en.y & 0xFFFFu) << 13));
        unsigned wb = en.y >> 16;
        int li = key - first;
        int r = atomicAdd(&ldsC[li], 1);
        csr[csr_base + ldsH[li] + r] = make_int2(partner, (int)(wb << 16));
        atomicAdd(&ldsW[li], b2f((ubf)wb));
    }
    __syncthreads();
    if (t < ncnt) dis[first + t] = rsqrtf(1.0f + ldsW[t]);   // self loop = 1
}

// ---------------- users: y0 = dis * l2norm(user_w) ----------------
__global__ void k_users(const float* __restrict__ user_w, const float* __restrict__ dis,
                        ubf* __restrict__ y0, float* __restrict__ acc, int use_acc) {
    int lane = threadIdx.x & 63;
    int wv = (blockIdx.x * blockDim.x + threadIdx.x) >> 6;
    int nw = (gridDim.x * blockDim.x) >> 6;
    for (int r = wv; r < U_CNT; r += nw) {
        int idx = r * 64 + lane;
        float v = user_w[idx];
        float ss = v * v;
        #pragma unroll
        for (int m = 32; m >= 1; m >>= 1) ss += __shfl_xor(ss, m, 64);
        float inv = dis[r] / fmaxf(sqrtf(ss), 1e-12f);
        float o = v * inv;
        y0[idx] = f2b(o);
        if (use_acc) acc[idx] = o;
    }
}

// ---------------- items: pure-streaming bf16-LDS GEMM, 4 items x 8 outs ----------------
__global__ void __launch_bounds__(256)
k_items(const float* __restrict__ audio, const ubf* __restrict__ metabuf,
        const float* __restrict__ Wp, const float* __restrict__ bp,
        const float* __restrict__ dis,
        ubf* __restrict__ yitem, float* __restrict__ accitem, int use_acc) {
    __shared__ __align__(16) ubf sXT[128 * XP];
    __shared__ __align__(16) ubf sW[128 * 64];
    int t = threadIdx.x;
    int base = blockIdx.x * IB;
    // stage Wp -> bf16
    {
        const float4* wg = (const float4*)Wp;
        #pragma unroll
        for (int r = 0; r < 8; ++r) {
            int idx = r * 256 + t;
            float4 v = wg[idx];
            ushort4 o = make_ushort4(f2b(v.x), f2b(v.y), f2b(v.z), f2b(v.w));
            *(ushort4*)&sW[idx * 4] = o;
        }
    }
    // stage audio -> sXT[f][i] transposed
    {
        const float4* g = (const float4*)audio + (size_t)base * 16;
        #pragma unroll
        for (int r = 0; r < 8; ++r) {
            int idx = r * 256 + t;               // 0..2047
            int i = idx >> 4, fq = idx & 15;
            float4 v = make_float4(0.f, 0.f, 0.f, 0.f);
            if (base + i < I_CNT) v = g[idx];
            sXT[(4 * fq + 0) * XP + i] = f2b(v.x);
            sXT[(4 * fq + 1) * XP + i] = f2b(v.y);
            sXT[(4 * fq + 2) * XP + i] = f2b(v.z);
            sXT[(4 * fq + 3) * XP + i] = f2b(v.w);
        }
    }
    // stage metabuf -> sXT[64+f][i]
    {
        const uint4* m4 = (const uint4*)(metabuf + (size_t)base * 64);
        #pragma unroll
        for (int r = 0; r < 4; ++r) {
            int idx = r * 256 + t;               // 0..1023
            int i = idx >> 3, c = idx & 7;
            uint4 m = make_uint4(0u, 0u, 0u, 0u);
            if (base + i < I_CNT) m = m4[idx];
            ubf* dp = &sXT[(64 + 8 * c) * XP + i];
            dp[0 * XP] = (ubf)(m.x & 0xffffu); dp[1 * XP] = (ubf)(m.x >> 16);
            dp[2 * XP] = (ubf)(m.y & 0xffffu); dp[3 * XP] = (ubf)(m.y >> 16);
            dp[4 * XP] = (ubf)(m.z & 0xffffu); dp[5 * XP] = (ubf)(m.z >> 16);
            dp[6 * XP] = (ubf)(m.w & 0xffffu); dp[7 * XP] = (ubf)(m.w >> 16);
        }
    }
    __syncthreads();
    int og = t & 7;                      // outs 8og..8og+7
    int igr = t >> 3;                    // items 4igr..4igr+3
    float c[4][8];
    {
        float bv[8];
        #pragma unroll
        for (int j = 0; j < 8; ++j) bv[j] = bp[8 * og + j];
        #pragma unroll
        for (int i = 0; i < 4; ++i)
            #pragma unroll
            for (int j = 0; j < 8; ++j) c[i][j] = bv[j];
    }
    const ubf* xcol = &sXT[4 * igr];
    const ubf* wrow = &sW[8 * og];
    #pragma unroll 2
    for (int k = 0; k < 128; ++k) {
        ushort4 xu = *(const ushort4*)&xcol[k * XP];
        uint4 wu = *(const uint4*)&wrow[k * 64];
        float x[4] = {b2f(xu.x), b2f(xu.y), b2f(xu.z), b2f(xu.w)};
        float w[8];
        unpack8(wu, w);
        #pragma unroll
        for (int i = 0; i < 4; ++i)
            #pragma unroll
            for (int j = 0; j < 8; ++j) c[i][j] = fmaf(x[i], w[j], c[i][j]);
    }
    #pragma unroll
    for (int i = 0; i < 4; ++i) {
        float ss = 0.f;
        #pragma unroll
        for (int j = 0; j < 8; ++j) ss += c[i][j] * c[i][j];
        ss += __shfl_xor(ss, 1, 64);
        ss += __shfl_xor(ss, 2, 64);
        ss += __shfl_xor(ss, 4, 64);
        int it = base + 4 * igr + i;
        if (it < I_CNT) {
            float q = dis[U_CNT + it] / fmaxf(sqrtf(ss), 1e-12f);
            uint4 o;
            o.x = pk2(c[i][0] * q, c[i][1] * q);
            o.y = pk2(c[i][2] * q, c[i][3] * q);
            o.z = pk2(c[i][4] * q, c[i][5] * q);
            o.w = pk2(c[i][6] * q, c[i][7] * q);
            *(uint4*)&yitem[(size_t)it * 64 + 8 * og] = o;
            if (use_acc) {
                float4* ap = (float4*)&accitem[(size_t)it * 64 + 8 * og];
                ap[0] = make_float4(c[i][0] * q, c[i][1] * q, c[i][2] * q, c[i][3] * q);
                ap[1] = make_float4(c[i][4] * q, c[i][5] * q, c[i][6] * q, c[i][7] * q);
            }
        }
    }
}

// ---------------- shared gather core: 8 nodes/wave, 8 lanes/node, uint4/lane ----------------
__device__ __forceinline__ void prop_gather(const int* __restrict__ offs,
                                            const int2* __restrict__ csr,
                                            const ubf* __restrict__ yin,
                                            int c, int s8, float* acc) {
    int e = offs[c], end = offs[c + 1];
    float bcc[8];
    #pragma unroll
    for (int i = 0; i < 8; ++i) bcc[i] = 0.f;
    for (; e + 7 < end; e += 8) {
        int2 c0 = csr[e], c1 = csr[e + 1], c2 = csr[e + 2], c3 = csr[e + 3];
        int2 c4 = csr[e + 4], c5 = csr[e + 5], c6 = csr[e + 6], c7 = csr[e + 7];
        uint4 g0 = *(const uint4*)&yin[(size_t)c0.x * 64 + s8];
        uint4 g1 = *(const uint4*)&yin[(size_t)c1.x * 64 + s8];
        uint4 g2 = *(const uint4*)&yin[(size_t)c2.x * 64 + s8];
        uint4 g3 = *(const uint4*)&yin[(size_t)c3.x * 64 + s8];
        uint4 g4 = *(const uint4*)&yin[(size_t)c4.x * 64 + s8];
        uint4 g5 = *(const uint4*)&yin[(size_t)c5.x * 64 + s8];
        uint4 g6 = *(const uint4*)&yin[(size_t)c6.x * 64 + s8];
        uint4 g7 = *(const uint4*)&yin[(size_t)c7.x * 64 + s8];
        float f[8];
        float w0 = __int_as_float(c0.y), w1 = __int_as_float(c1.y);
        float w2 = __int_as_float(c2.y), w3 = __int_as_float(c3.y);
        float w4 = __int_as_float(c4.y), w5 = __int_as_float(c5.y);
        float w6 = __int_as_float(c6.y), w7 = __int_as_float(c7.y);
        unpack8(g0, f);
        #pragma unroll
        for (int i = 0; i < 8; ++i) acc[i] = fmaf(w0, f[i], acc[i]);
        unpack8(g1, f);
        #pragma unroll
        for (int i = 0; i < 8; ++i) bcc[i] = fmaf(w1, f[i], bcc[i]);
        unpack8(g2, f);
        #pragma unroll
        for (int i = 0; i < 8; ++i) acc[i] = fmaf(w2, f[i], acc[i]);
        unpack8(g3, f);
        #pragma unroll
        for (int i = 0; i < 8; ++i) bcc[i] = fmaf(w3, f[i], bcc[i]);
        unpack8(g4, f);
        #pragma unroll
        for (int i = 0; i < 8; ++i) acc[i] = fmaf(w4, f[i], acc[i]);
        unpack8(g5, f);
        #pragma unroll
        for (int i = 0; i < 8; ++i) bcc[i] = fmaf(w5, f[i], bcc[i]);
        unpack8(g6, f);
        #pragma unroll
        for (int i = 0; i < 8; ++i) acc[i] = fmaf(w6, f[i], acc[i]);
        unpack8(g7, f);
        #pragma unroll
        for (int i = 0; i < 8; ++i) bcc[i] = fmaf(w7, f[i], bcc[i]);
    }
    for (; e + 3 < end; e += 4) {
        int2 c0 = csr[e], c1 = csr[e + 1], c2 = csr[e + 2], c3 = csr[e + 3];
        uint4 g0 = *(const uint4*)&yin[(size_t)c0.x * 64 + s8];
        uint4 g1 = *(const uint4*)&yin[(size_t)c1.x * 64 + s8];
        uint4 g2 = *(const uint4*)&yin[(size_t)c2.x * 64 + s8];
        uint4 g3 = *(const uint4*)&yin[(size_t)c3.x * 64 + s8];
        float f[8];
        float w0 = __int_as_float(c0.y), w1 = __int_as_float(c1.y);
        float w2 = __int_as_float(c2.y), w3 = __int_as_float(c3.y);
        unpack8(g0, f);
        #pragma unroll
        for (int i = 0; i < 8; ++i) acc[i] = fmaf(w0, f[i], acc[i]);
        unpack8(g1, f);
        #pragma unroll
        for (int i = 0; i < 8; ++i) bcc[i] = fmaf(w1, f[i], bcc[i]);
        unpack8(g2, f);
        #pragma unroll
        for (int i = 0; i < 8; ++i) acc[i] = fmaf(w2, f[i], acc[i]);
        unpack8(g3, f);
        #pragma unroll
        for (int i = 0; i < 8; ++i) bcc[i] = fmaf(w3, f[i], bcc[i]);
    }
    for (; e < end; ++e) {
        int2 cc = csr[e];
        uint4 gg = *(const uint4*)&yin[(size_t)cc.x * 64 + s8];
        float f[8];
        float ww = __int_as_float(cc.y);
        unpack8(gg, f);
        #pragma unroll
        for (int i = 0; i < 8; ++i) acc[i] = fmaf(ww, f[i], acc[i]);
    }
    #pragma unroll
    for (int i = 0; i < 8; ++i) acc[i] += bcc[i];
}

// ---------------- LGConv round: 8 nodes/wave, 8 lanes/node ----------------
__global__ void k_prop(const int* __restrict__ offs, const int2* __restrict__ csr,
                       const float* __restrict__ dis,
                       const ubf* __restrict__ yin, ubf* __restrict__ yout,
                       float* __restrict__ acc, int use_acc) {
    int lane = threadIdx.x & 63;
    int g = lane >> 3;                   // node group 0..7
    int s8 = (lane & 7) * 8;             // dims s8..s8+7
    int wv = (blockIdx.x * 256 + threadIdx.x) >> 6;
    int c = wv * 8 + g;
    if (c >= N_CNT) return;
    float dc = dis[c];
    float a[8];
    #pragma unroll
    for (int i = 0; i < 8; ++i) a[i] = 0.f;
    prop_gather(offs, csr, yin, c, s8, a);
    size_t idx = (size_t)c * 64 + s8;
    uint4 sv = *(const uint4*)&yin[idx];
    float sf[8];
    unpack8(sv, sf);
    float dc2 = dc * dc;
    float r[8];
    #pragma unroll
    for (int i = 0; i < 8; ++i) r[i] = dc2 * (a[i] + sf[i]);
    uint4 o;
    o.x = pk2(r[0], r[1]); o.y = pk2(r[2], r[3]);
    o.z = pk2(r[4], r[5]); o.w = pk2(r[6], r[7]);
    *(uint4*)&yout[idx] = o;
    if (use_acc) {
        float4* ap = (float4*)&acc[idx];
        float4 a0 = ap[0], a1 = ap[1];
        a0.x += r[0]; a0.y += r[1]; a0.z += r[2]; a0.w += r[3];
        a1.x += r[4]; a1.y += r[5]; a1.z += r[6]; a1.w += r[7];
        ap[0] = a0; ap[1] = a1;
    }
}

// ---------------- final round fused with layer-sum + l2norm epilogue ----------------
__global__ void k_prop_fin(const int* __restrict__ offs, const int2* __restrict__ csr,
                           const float* __restrict__ dis,
                           const ubf* __restrict__ y0, const ubf* __restrict__ y1,
                           const ubf* __restrict__ yin, float* __restrict__ out) {
    int lane = threadIdx.x & 63;
    int g = lane >> 3;
    int s8 = (lane & 7) * 8;
    int wv = (blockIdx.x * 256 + threadIdx.x) >> 6;
    int c = wv * 8 + g;
    if (c >= N_CNT) return;
    float dc = dis[c];
    float a[8];
    #pragma unroll
    for (int i = 0; i < 8; ++i) a[i] = 0.f;
    prop_gather(offs, csr, yin, c, s8, a);
    size_t idx = (size_t)c * 64 + s8;
    uint4 sv = *(const uint4*)&yin[idx];
    uint4 v0u = *(const uint4*)&y0[idx];
    uint4 v1u = *(const uint4*)&y1[idx];
    float sf[8], f0[8], f1[8];
    unpack8(sv, sf);
    unpack8(v0u, f0);
    unpack8(v1u, f1);
    float dc2 = dc * dc;
    float v[8];
    float ss = 0.f;
    #pragma unroll
    for (int i = 0; i < 8; ++i) {
        float r = dc2 * (a[i] + sf[i]);            // y3 unrounded
        v[i] = (f0[i] + f1[i]) + (sf[i] + r);
        ss = fmaf(v[i], v[i], ss);
    }
    ss += __shfl_xor(ss, 1, 64);
    ss += __shfl_xor(ss, 2, 64);
    ss += __shfl_xor(ss, 4, 64);
    float inv = 1.0f / fmaxf(sqrtf(ss), 1e-12f);
    float4* op = (float4*)&out[idx];
    op[0] = make_float4(v[0] * inv, v[1] * inv, v[2] * inv, v[3] * inv);
    op[1] = make_float4(v[4] * inv, v[5] * inv, v[6] * inv, v[7] * inv);
}

// ---------------- epilogue A: l2norm(acc)  (acc fp32, may alias out) ----------------
__global__ void k_final_acc(const float* __restrict__ acc, float* __restrict__ out) {
    int lane = threadIdx.x & 63;
    int c = (blockIdx.x * 256 + threadIdx.x) >> 6;
    if (c >= N_CNT) return;
    int idx = c * 64 + lane;
    float v = acc[idx];
    float ss = v * v;
    #pragma unroll
    for (int m = 32; m >= 1; m >>= 1) ss += __shfl_xor(ss, m, 64);
    out[idx] = v / fmaxf(sqrtf(ss), 1e-12f);
}

extern "C" void kernel_launch(void* const* d_in, const int* in_sizes, int n_in,
                              void* d_out, int out_size, void* d_ws, size_t ws_size,
                              hipStream_t stream) {
    const int*   edge_src   = (const int*)  d_in[0];
    const int*   edge_dst   = (const int*)  d_in[1];
    const float* edge_attr  = (const float*)d_in[2];
    const float* user_w     = (const float*)d_in[3];
    const float* artist_w   = (const float*)d_in[4];
    const float* album_w    = (const float*)d_in[5];
    const float* item_audio = (const float*)d_in[6];
    const int*   artist_ids = (const int*)  d_in[7];
    const int*   album_ids  = (const int*)  d_in[8];
    const float* Wp         = (const float*)d_in[9];
    const float* bp         = (const float*)d_in[10];
    const float* W1         = (const float*)d_in[11];
    const float* b1         = (const float*)d_in[12];
    const float* W2         = (const float*)d_in[13];
    const float* b2         = (const float*)d_in[14];

    char* p = (char*)d_ws;
    auto carve = [&](size_t bytes) -> void* {
        void* q = (void*)p;
        p += (bytes + 255) & ~(size_t)255;
        return q;
    };
    // common carve (~31 MB)
    float* dis    = (float*)carve((size_t)N_CNT * 4);
    int*   offs   = (int*)  carve((size_t)(N_CNT + 1) * 4);
    int*   gcur   = (int*)  carve((size_t)NBUCK * 4);
    int2*  csr    = (int2*) carve((size_t)2 * E_CNT * 8);
    ubf*   metabuf= (ubf*)  carve((size_t)I_CNT * 64 * 2);  // 12.8 MB bf16
    const size_t YB = (size_t)N_CNT * 64 * 2;      // 38.4 MB per bf16 y buffer
    const size_t EBUF = (size_t)NBUCK * BCAP * 8;  // 28.8 MB entry buffer
    size_t used = (size_t)(p - (char*)d_ws);
    // Path B (no acc RMW) needs y0,y1,y2 bf16 in ws; ebuf aliases y2 (dead
    // until prop round 2). Else ping-pong + fp32 acc in d_out.
    int no_acc = (ws_size >= used + 3 * YB + (size_t)4096) ? 1 : 0;
    ubf *y0, *y1, *y2;
    uint2* ebuf;
    float* acc = nullptr;
    if (no_acc) {
        y0 = (ubf*)carve(YB);
        y1 = (ubf*)carve(YB);
        y2 = (ubf*)carve(YB);
        ebuf = (uint2*)y2;             // alias: 38.4MB >= 28.8MB
    } else {
        y0 = (ubf*)carve(YB);
        y1 = (ubf*)carve(YB);
        y2 = y0;
        acc = (float*)d_out;           // fp32 accumulator lives in d_out
        ebuf = (uint2*)carve(EBUF);
    }
    (void)in_sizes; (void)n_in; (void)out_size;

    hipMemsetAsync(gcur, 0, (size_t)NBUCK * 4, stream);
    // bin1 blocks first (atomic-latency role), meta role blocks fill behind
    k_bin1 <<<NB_BIN1 + NB_META5, 512, 0, stream>>>(
        edge_src, edge_dst, edge_attr, W1, b1, W2, b2, ebuf, gcur,
        artist_w, album_w, artist_ids, album_ids, metabuf);
    k_bin2 <<<NBUCK, 1024, 0, stream>>>(ebuf, gcur, offs, csr, dis);
    k_users<<<1024, 256, 0, stream>>>(user_w, dis, y0, acc, no_acc ? 0 : 1);
    k_items<<<NB_I, 256, 0, stream>>>(item_audio, metabuf, Wp, bp, dis,
                                      y0 + (size_t)U_CNT * 64,
                                      no_acc ? nullptr : acc + (size_t)U_CNT * 64,
                                      no_acc ? 0 : 1);
    // 8 nodes per wave -> N/8 waves -> N/32 blocks of 256
    const int PROP_BLKS = N_CNT / 32;    // 9375
    if (no_acc) {
        k_prop<<<PROP_BLKS, 256, 0, stream>>>(offs, csr, dis, y0, y1, nullptr, 0);
        k_prop<<<PROP_BLKS, 256, 0, stream>>>(offs, csr, dis, y1, y2, nullptr, 0);
        k_prop_fin<<<PROP_BLKS, 256, 0, stream>>>(offs, csr, dis, y0, y1, y2,
                                                  (float*)d_out);
    } else {
        // y0 -> y1 -> y0 -> y1 (bf16), accumulating fp32 into acc (= d_out)
        k_prop<<<PROP_BLKS, 256, 0, stream>>>(offs, csr, dis, y0, y1, acc, 1);
        k_prop<<<PROP_BLKS, 256, 0, stream>>>(offs, csr, dis, y1, y0, acc, 1);
        k_prop<<<PROP_BLKS, 256, 0, stream>>>(offs, csr, dis, y0, y1, acc, 1);
        k_final_acc<<<N_CNT / 4, 256, 0, stream>>>(acc, (float*)d_out);
    }
}

// Round 13
// 480.179 us; speedup vs baseline: 1.1456x; 1.0401x over previous
//
#include <hip/hip_runtime.h>
#include <hip/hip_bf16.h>

#define U_CNT 200000
#define I_CNT 100000
#define N_CNT 300000
#define E_CNT 1000000
#define ATTR_D 8
#define H_DIM 32
#define IB 128                               // items per item-block
#define NB_I ((I_CNT + IB - 1) / IB)         // 782 item blocks
#define XP 130                               // sXT pitch (bf16 elems)

// binning parameters
#define BSHIFT 10                            // 1024 nodes per bucket
#define NBUCK 293                            // ceil(300000/1024)
#define BCAP 12288                           // entries capacity/bucket (= 12*1024)
#define EPB 2048                             // edges per bin1 block
#define NB_BIN1 ((E_CNT + EPB - 1) / EPB)    // 489
#define NB_META5 (I_CNT / 32)                // 3125 meta-role blocks (512 thr)

// NOTE (rounds 1-4): all float inputs / output FLOAT32. absmax floor 1.95e-3
// == bf16 rounding of reference; threshold 1.26e-2.
// NOTE (round 7): rank-capture scatter + y-space reform. 1098 -> 951 us.
// NOTE (round 8/13/14): k_items LDS GEMM; real fix was splitting serial
// meta-gather into k_meta (4 rows/vmem instr).
// NOTE (round 9): bf16 y-storage. round 10: k_prop 4 nodes/wave. GATHERS =
// latency x concurrency (in-flight rows per wave is the lever).
// NOTE (round 11): fusing latency-bound role with BIG-LDS role regressed.
// NOTE (round 12): per-thread batching regressed for ATOMICS.
// NOTE (round 15): 2-phase bucket binning CSR build. 615 -> 547.
// NOTE (round 17): fusion pass (deg->bin2, final_sum->prop_fin). 550 -> 513.
// NOTE (round 18): 8 nodes/wave prop + meta-role fused into bin1 + shfl
// scan. 513 -> 499; prop_fin at 3.8 TB/s (47% peak).
// NOTE (round 19, this round): (a) k_bin2 single-pass: entries register-
// resident (12/thread, fully unrolled -> no scratch), kills the 28.8MB
// ebuf re-read. (b) prop gather: clamped always-8 batches (idx=min(e+i,
// end-1), w masked 0) — deg<8 nodes now keep 8 rows in flight instead of
// 4-5 with a dependent tail; duplicate gathers are L2 hits; +0*f is exact.

typedef unsigned short ubf;

__device__ __forceinline__ float b2f(ubf b) {
    return __uint_as_float((unsigned)b << 16);
}
__device__ __forceinline__ ubf f2b(float v) {
    unsigned u = __float_as_uint(v);
    u += 0x7fffu + ((u >> 16) & 1u);           // round to nearest even
    return (ubf)(u >> 16);
}
__device__ __forceinline__ unsigned pk2(float lo, float hi) {
    return (unsigned)f2b(lo) | ((unsigned)f2b(hi) << 16);
}
// unpack 8 bf16 (uint4) -> 8 f32
__device__ __forceinline__ void unpack8(uint4 g, float f[8]) {
    f[0] = __uint_as_float(g.x << 16); f[1] = __uint_as_float(g.x & 0xffff0000u);
    f[2] = __uint_as_float(g.y << 16); f[3] = __uint_as_float(g.y & 0xffff0000u);
    f[4] = __uint_as_float(g.z << 16); f[5] = __uint_as_float(g.z & 0xffff0000u);
    f[6] = __uint_as_float(g.w << 16); f[7] = __uint_as_float(g.w & 0xffff0000u);
}
// entry pack: x = key[0:19) | (partner&0x1FFF)<<19 ; y = partner>>13 | wb<<16
__device__ __forceinline__ uint2 packE(int key, int partner, unsigned wb) {
    return make_uint2((unsigned)key | (((unsigned)partner & 0x1FFFu) << 19),
                     ((unsigned)partner >> 13) | (wb << 16));
}

// ---------------- phase 1: edge MLP + binning | meta-gather role ----------------
__global__ void __launch_bounds__(512)
k_bin1(const int* __restrict__ src, const int* __restrict__ dst,
       const float* __restrict__ attr,
       const float* __restrict__ W1, const float* __restrict__ b1,
       const float* __restrict__ W2, const float* __restrict__ b2,
       uint2* __restrict__ ebuf, int* __restrict__ gcur,
       const float* __restrict__ art, const float* __restrict__ alb,
       const int* __restrict__ aid, const int* __restrict__ alid,
       ubf* __restrict__ metabuf) {
    __shared__ float sW1[ATTR_D * H_DIM];
    __shared__ float sb1[H_DIM];
    __shared__ float sW2[H_DIM];
    __shared__ float sb2;
    __shared__ int hist[NBUCK];
    __shared__ int basem[NBUCK];
    int t = threadIdx.x;
    int bx = blockIdx.x;
    if (bx >= NB_BIN1) {
        // -------- meta role: 4 items/wave, 16 lanes/item, float4/lane --------
        int lane = t & 63;
        int g = lane >> 4;
        int q = lane & 15;
        int wv = ((bx - NB_BIN1) * 512 + t) >> 6;
        int it = wv * 4 + g;                 // exact: NB_META5*8 waves * 4 = I_CNT
        if (it >= I_CNT) return;
        int a_ = aid[it], al_ = alid[it];
        float4 va = *(const float4*)&art[(size_t)a_ * 64 + q * 4];
        float4 vb = *(const float4*)&alb[(size_t)al_ * 64 + q * 4];
        ushort4 o = make_ushort4(f2b(va.x + vb.x), f2b(va.y + vb.y),
                                 f2b(va.z + vb.z), f2b(va.w + vb.w));
        *(ushort4*)&metabuf[(size_t)it * 64 + q * 4] = o;
        return;
    }
    // -------- bin1 role --------
    if (t < 256) sW1[t] = W1[t];
    if (t < H_DIM) { sb1[t] = b1[t]; sW2[t] = W2[t]; }
    if (t == 0) sb2 = b2[0];
    for (int i = t; i < NBUCK; i += 512) hist[i] = 0;
    __syncthreads();
    int ebase = bx * EPB;
    int sarr[4], darr[4];
    unsigned warr[4];
    #pragma unroll
    for (int k = 0; k < 4; ++k) {
        int e = ebase + k * 512 + t;
        sarr[k] = -1;
        if (e < E_CNT) {
            const float4* a4 = (const float4*)attr + (size_t)e * 2;
            float4 r0 = a4[0];
            float4 r1 = a4[1];
            float a[8] = {r0.x, r0.y, r0.z, r0.w, r1.x, r1.y, r1.z, r1.w};
            float z = sb2;
            #pragma unroll
            for (int h = 0; h < H_DIM; ++h) {
                float acc = sb1[h];
                #pragma unroll
                for (int kk = 0; kk < 8; ++kk) acc = fmaf(a[kk], sW1[kk * H_DIM + h], acc);
                acc = fmaxf(acc, 0.0f);
                z = fmaf(acc, sW2[h], z);
            }
            float w = 1.0f / (1.0f + __expf(-z));
            w = fmaxf(w, 1e-6f);
            int s = src[e], d = U_CNT + dst[e];
            sarr[k] = s; darr[k] = d; warr[k] = (unsigned)f2b(w);
            atomicAdd(&hist[s >> BSHIFT], 1);
            atomicAdd(&hist[d >> BSHIFT], 1);
        }
    }
    __syncthreads();
    for (int i = t; i < NBUCK; i += 512) {
        int h = hist[i];
        basem[i] = (h > 0) ? (i * BCAP + atomicAdd(&gcur[i], h)) : 0;
    }
    __syncthreads();
    for (int i = t; i < NBUCK; i += 512) hist[i] = 0;   // reuse as cursor
    __syncthreads();
    #pragma unroll
    for (int k = 0; k < 4; ++k) {
        if (sarr[k] >= 0) {
            int s = sarr[k], d = darr[k];
            unsigned wb = warr[k];
            int bs = s >> BSHIFT;
            int r = atomicAdd(&hist[bs], 1);
            ebuf[(size_t)basem[bs] + r] = packE(s, d, wb);
            int bd = d >> BSHIFT;
            r = atomicAdd(&hist[bd], 1);
            ebuf[(size_t)basem[bd] + r] = packE(d, s, wb);
        }
    }
}

// ---------------- phase 2: per-bucket CSR build, single ebuf pass ----------------
__global__ void __launch_bounds__(1024)
k_bin2(const uint2* __restrict__ ebuf, const int* __restrict__ gcur,
       int* __restrict__ offs, int2* __restrict__ csr,
       float* __restrict__ dis) {
    __shared__ int ldsCnt[NBUCK];
    __shared__ int ldsH[1024];
    __shared__ int ldsC[1024];
    __shared__ float ldsW[1024];
    __shared__ int ldsT[16];
    __shared__ int sMeta[2];          // csr_base, mycount
    int t = threadIdx.x;
    int b = blockIdx.x;
    if (t < NBUCK) ldsCnt[t] = gcur[t];   // gcur is delta-based: == count
    ldsH[t] = 0;
    ldsC[t] = 0;
    ldsW[t] = 0.0f;
    __syncthreads();
    if (t == 0) {
        int base = 0;
        for (int i = 0; i < b; ++i) base += ldsCnt[i];
        sMeta[0] = base;
        sMeta[1] = ldsCnt[b];
    }
    __syncthreads();
    int csr_base = sMeta[0], mycount = sMeta[1];
    size_t eb = (size_t)b * BCAP;
    int first = b << BSHIFT;
    // single global read: entries register-resident (<=12/thread, unrolled)
    uint2 ent[12];
    #pragma unroll
    for (int i = 0; i < 12; ++i) {
        int idx = i * 1024 + t;
        if (idx < mycount) ent[i] = ebuf[eb + idx];
    }
    // node histogram from registers
    #pragma unroll
    for (int i = 0; i < 12; ++i) {
        int idx = i * 1024 + t;
        if (idx < mycount) atomicAdd(&ldsH[(ent[i].x & 0x7FFFFu) - first], 1);
    }
    __syncthreads();
    // exclusive scan of 1024 counters: wave shfl scan + 16 wave-sums
    int v0 = ldsH[t];
    int incl = v0;
    #pragma unroll
    for (int off = 1; off < 64; off <<= 1) {
        int x = __shfl_up(incl, off, 64);
        if ((t & 63) >= off) incl += x;
    }
    int w = t >> 6;
    if ((t & 63) == 63) ldsT[w] = incl;
    __syncthreads();
    if (t == 0) {
        int run = 0;
        #pragma unroll
        for (int i = 0; i < 16; ++i) { int x = ldsT[i]; ldsT[i] = run; run += x; }
    }
    __syncthreads();
    int excl = ldsT[w] + incl - v0;
    ldsH[t] = excl;                   // ldsH now exclusive offsets
    __syncthreads();
    int ncnt = min(1024, N_CNT - first);
    if (t < ncnt) offs[first + t] = csr_base + ldsH[t];
    if (b == NBUCK - 1 && t == 0) offs[N_CNT] = 2 * E_CNT;
    // scatter register entries to final CSR + accumulate deg in LDS
    #pragma unroll
    for (int i = 0; i < 12; ++i) {
        int idx = i * 1024 + t;
        if (idx < mycount) {
            uint2 en = ent[i];
            int key = (int)(en.x & 0x7FFFFu);
            int partner = (int)((en.x >> 19) | ((en.y & 0xFFFFu) << 13));
            unsigned wb = en.y >> 16;
            int li = key - first;
            int r = atomicAdd(&ldsC[li], 1);
            csr[csr_base + ldsH[li] + r] = make_int2(partner, (int)(wb << 16));
            atomicAdd(&ldsW[li], b2f((ubf)wb));
        }
    }
    __syncthreads();
    if (t < ncnt) dis[first + t] = rsqrtf(1.0f + ldsW[t]);   // self loop = 1
}

// ---------------- users: y0 = dis * l2norm(user_w) ----------------
__global__ void k_users(const float* __restrict__ user_w, const float* __restrict__ dis,
                        ubf* __restrict__ y0, float* __restrict__ acc, int use_acc) {
    int lane = threadIdx.x & 63;
    int wv = (blockIdx.x * blockDim.x + threadIdx.x) >> 6;
    int nw = (gridDim.x * blockDim.x) >> 6;
    for (int r = wv; r < U_CNT; r += nw) {
        int idx = r * 64 + lane;
        float v = user_w[idx];
        float ss = v * v;
        #pragma unroll
        for (int m = 32; m >= 1; m >>= 1) ss += __shfl_xor(ss, m, 64);
        float inv = dis[r] / fmaxf(sqrtf(ss), 1e-12f);
        float o = v * inv;
        y0[idx] = f2b(o);
        if (use_acc) acc[idx] = o;
    }
}

// ---------------- items: pure-streaming bf16-LDS GEMM, 4 items x 8 outs ----------------
__global__ void __launch_bounds__(256)
k_items(const float* __restrict__ audio, const ubf* __restrict__ metabuf,
        const float* __restrict__ Wp, const float* __restrict__ bp,
        const float* __restrict__ dis,
        ubf* __restrict__ yitem, float* __restrict__ accitem, int use_acc) {
    __shared__ __align__(16) ubf sXT[128 * XP];
    __shared__ __align__(16) ubf sW[128 * 64];
    int t = threadIdx.x;
    int base = blockIdx.x * IB;
    // stage Wp -> bf16
    {
        const float4* wg = (const float4*)Wp;
        #pragma unroll
        for (int r = 0; r < 8; ++r) {
            int idx = r * 256 + t;
            float4 v = wg[idx];
            ushort4 o = make_ushort4(f2b(v.x), f2b(v.y), f2b(v.z), f2b(v.w));
            *(ushort4*)&sW[idx * 4] = o;
        }
    }
    // stage audio -> sXT[f][i] transposed
    {
        const float4* g = (const float4*)audio + (size_t)base * 16;
        #pragma unroll
        for (int r = 0; r < 8; ++r) {
            int idx = r * 256 + t;               // 0..2047
            int i = idx >> 4, fq = idx & 15;
            float4 v = make_float4(0.f, 0.f, 0.f, 0.f);
            if (base + i < I_CNT) v = g[idx];
            sXT[(4 * fq + 0) * XP + i] = f2b(v.x);
            sXT[(4 * fq + 1) * XP + i] = f2b(v.y);
            sXT[(4 * fq + 2) * XP + i] = f2b(v.z);
            sXT[(4 * fq + 3) * XP + i] = f2b(v.w);
        }
    }
    // stage metabuf -> sXT[64+f][i]
    {
        const uint4* m4 = (const uint4*)(metabuf + (size_t)base * 64);
        #pragma unroll
        for (int r = 0; r < 4; ++r) {
            int idx = r * 256 + t;               // 0..1023
            int i = idx >> 3, c = idx & 7;
            uint4 m = make_uint4(0u, 0u, 0u, 0u);
            if (base + i < I_CNT) m = m4[idx];
            ubf* dp = &sXT[(64 + 8 * c) * XP + i];
            dp[0 * XP] = (ubf)(m.x & 0xffffu); dp[1 * XP] = (ubf)(m.x >> 16);
            dp[2 * XP] = (ubf)(m.y & 0xffffu); dp[3 * XP] = (ubf)(m.y >> 16);
            dp[4 * XP] = (ubf)(m.z & 0xffffu); dp[5 * XP] = (ubf)(m.z >> 16);
            dp[6 * XP] = (ubf)(m.w & 0xffffu); dp[7 * XP] = (ubf)(m.w >> 16);
        }
    }
    __syncthreads();
    int og = t & 7;                      // outs 8og..8og+7
    int igr = t >> 3;                    // items 4igr..4igr+3
    float c[4][8];
    {
        float bv[8];
        #pragma unroll
        for (int j = 0; j < 8; ++j) bv[j] = bp[8 * og + j];
        #pragma unroll
        for (int i = 0; i < 4; ++i)
            #pragma unroll
            for (int j = 0; j < 8; ++j) c[i][j] = bv[j];
    }
    const ubf* xcol = &sXT[4 * igr];
    const ubf* wrow = &sW[8 * og];
    #pragma unroll 2
    for (int k = 0; k < 128; ++k) {
        ushort4 xu = *(const ushort4*)&xcol[k * XP];
        uint4 wu = *(const uint4*)&wrow[k * 64];
        float x[4] = {b2f(xu.x), b2f(xu.y), b2f(xu.z), b2f(xu.w)};
        float w[8];
        unpack8(wu, w);
        #pragma unroll
        for (int i = 0; i < 4; ++i)
            #pragma unroll
            for (int j = 0; j < 8; ++j) c[i][j] = fmaf(x[i], w[j], c[i][j]);
    }
    #pragma unroll
    for (int i = 0; i < 4; ++i) {
        float ss = 0.f;
        #pragma unroll
        for (int j = 0; j < 8; ++j) ss += c[i][j] * c[i][j];
        ss += __shfl_xor(ss, 1, 64);
        ss += __shfl_xor(ss, 2, 64);
        ss += __shfl_xor(ss, 4, 64);
        int it = base + 4 * igr + i;
        if (it < I_CNT) {
            float q = dis[U_CNT + it] / fmaxf(sqrtf(ss), 1e-12f);
            uint4 o;
            o.x = pk2(c[i][0] * q, c[i][1] * q);
            o.y = pk2(c[i][2] * q, c[i][3] * q);
            o.z = pk2(c[i][4] * q, c[i][5] * q);
            o.w = pk2(c[i][6] * q, c[i][7] * q);
            *(uint4*)&yitem[(size_t)it * 64 + 8 * og] = o;
            if (use_acc) {
                float4* ap = (float4*)&accitem[(size_t)it * 64 + 8 * og];
                ap[0] = make_float4(c[i][0] * q, c[i][1] * q, c[i][2] * q, c[i][3] * q);
                ap[1] = make_float4(c[i][4] * q, c[i][5] * q, c[i][6] * q, c[i][7] * q);
            }
        }
    }
}

// ---------------- gather core: 8 nodes/wave, 8 lanes/node, clamped 8-batches ----------------
__device__ __forceinline__ void prop_gather(const int* __restrict__ offs,
                                            const int2* __restrict__ csr,
                                            const ubf* __restrict__ yin,
                                            int c, int s8, float* acc) {
    int e = offs[c], end = offs[c + 1];
    float bcc[8];
    #pragma unroll
    for (int i = 0; i < 8; ++i) bcc[i] = 0.f;
    int last = end - 1;
    for (; e < end; e += 8) {
        int i1 = min(e + 1, last), i2 = min(e + 2, last), i3 = min(e + 3, last);
        int i4 = min(e + 4, last), i5 = min(e + 5, last), i6 = min(e + 6, last);
        int i7 = min(e + 7, last);
        int2 c0 = csr[e],  c1 = csr[i1], c2 = csr[i2], c3 = csr[i3];
        int2 c4 = csr[i4], c5 = csr[i5], c6 = csr[i6], c7 = csr[i7];
        uint4 g0 = *(const uint4*)&yin[(size_t)c0.x * 64 + s8];
        uint4 g1 = *(const uint4*)&yin[(size_t)c1.x * 64 + s8];
        uint4 g2 = *(const uint4*)&yin[(size_t)c2.x * 64 + s8];
        uint4 g3 = *(const uint4*)&yin[(size_t)c3.x * 64 + s8];
        uint4 g4 = *(const uint4*)&yin[(size_t)c4.x * 64 + s8];
        uint4 g5 = *(const uint4*)&yin[(size_t)c5.x * 64 + s8];
        uint4 g6 = *(const uint4*)&yin[(size_t)c6.x * 64 + s8];
        uint4 g7 = *(const uint4*)&yin[(size_t)c7.x * 64 + s8];
        float w0 = __int_as_float(c0.y);
        float w1 = (e + 1 < end) ? __int_as_float(c1.y) : 0.f;
        float w2 = (e + 2 < end) ? __int_as_float(c2.y) : 0.f;
        float w3 = (e + 3 < end) ? __int_as_float(c3.y) : 0.f;
        float w4 = (e + 4 < end) ? __int_as_float(c4.y) : 0.f;
        float w5 = (e + 5 < end) ? __int_as_float(c5.y) : 0.f;
        float w6 = (e + 6 < end) ? __int_as_float(c6.y) : 0.f;
        float w7 = (e + 7 < end) ? __int_as_float(c7.y) : 0.f;
        float f[8];
        unpack8(g0, f);
        #pragma unroll
        for (int i = 0; i < 8; ++i) acc[i] = fmaf(w0, f[i], acc[i]);
        unpack8(g1, f);
        #pragma unroll
        for (int i = 0; i < 8; ++i) bcc[i] = fmaf(w1, f[i], bcc[i]);
        unpack8(g2, f);
        #pragma unroll
        for (int i = 0; i < 8; ++i) acc[i] = fmaf(w2, f[i], acc[i]);
        unpack8(g3, f);
        #pragma unroll
        for (int i = 0; i < 8; ++i) bcc[i] = fmaf(w3, f[i], bcc[i]);
        unpack8(g4, f);
        #pragma unroll
        for (int i = 0; i < 8; ++i) acc[i] = fmaf(w4, f[i], acc[i]);
        unpack8(g5, f);
        #pragma unroll
        for (int i = 0; i < 8; ++i) bcc[i] = fmaf(w5, f[i], bcc[i]);
        unpack8(g6, f);
        #pragma unroll
        for (int i = 0; i < 8; ++i) acc[i] = fmaf(w6, f[i], acc[i]);
        unpack8(g7, f);
        #pragma unroll
        for (int i = 0; i < 8; ++i) bcc[i] = fmaf(w7, f[i], bcc[i]);
    }
    #pragma unroll
    for (int i = 0; i < 8; ++i) acc[i] += bcc[i];
}

// ---------------- LGConv round: 8 nodes/wave, 8 lanes/node ----------------
__global__ void k_prop(const int* __restrict__ offs, const int2* __restrict__ csr,
                       const float* __restrict__ dis,
                       const ubf* __restrict__ yin, ubf* __restrict__ yout,
                       float* __restrict__ acc, int use_acc) {
    int lane = threadIdx.x & 63;
    int g = lane >> 3;                   // node group 0..7
    int s8 = (lane & 7) * 8;             // dims s8..s8+7
    int wv = (blockIdx.x * 256 + threadIdx.x) >> 6;
    int c = wv * 8 + g;
    if (c >= N_CNT) return;
    float dc = dis[c];
    float a[8];
    #pragma unroll
    for (int i = 0; i < 8; ++i) a[i] = 0.f;
    prop_gather(offs, csr, yin, c, s8, a);
    size_t idx = (size_t)c * 64 + s8;
    uint4 sv = *(const uint4*)&yin[idx];
    float sf[8];
    unpack8(sv, sf);
    float dc2 = dc * dc;
    float r[8];
    #pragma unroll
    for (int i = 0; i < 8; ++i) r[i] = dc2 * (a[i] + sf[i]);
    uint4 o;
    o.x = pk2(r[0], r[1]); o.y = pk2(r[2], r[3]);
    o.z = pk2(r[4], r[5]); o.w = pk2(r[6], r[7]);
    *(uint4*)&yout[idx] = o;
    if (use_acc) {
        float4* ap = (float4*)&acc[idx];
        float4 a0 = ap[0], a1 = ap[1];
        a0.x += r[0]; a0.y += r[1]; a0.z += r[2]; a0.w += r[3];
        a1.x += r[4]; a1.y += r[5]; a1.z += r[6]; a1.w += r[7];
        ap[0] = a0; ap[1] = a1;
    }
}

// ---------------- final round fused with layer-sum + l2norm epilogue ----------------
__global__ void k_prop_fin(const int* __restrict__ offs, const int2* __restrict__ csr,
                           const float* __restrict__ dis,
                           const ubf* __restrict__ y0, const ubf* __restrict__ y1,
                           const ubf* __restrict__ yin, float* __restrict__ out) {
    int lane = threadIdx.x & 63;
    int g = lane >> 3;
    int s8 = (lane & 7) * 8;
    int wv = (blockIdx.x * 256 + threadIdx.x) >> 6;
    int c = wv * 8 + g;
    if (c >= N_CNT) return;
    float dc = dis[c];
    float a[8];
    #pragma unroll
    for (int i = 0; i < 8; ++i) a[i] = 0.f;
    prop_gather(offs, csr, yin, c, s8, a);
    size_t idx = (size_t)c * 64 + s8;
    uint4 sv = *(const uint4*)&yin[idx];
    uint4 v0u = *(const uint4*)&y0[idx];
    uint4 v1u = *(const uint4*)&y1[idx];
    float sf[8], f0[8], f1[8];
    unpack8(sv, sf);
    unpack8(v0u, f0);
    unpack8(v1u, f1);
    float dc2 = dc * dc;
    float v[8];
    float ss = 0.f;
    #pragma unroll
    for (int i = 0; i < 8; ++i) {
        float r = dc2 * (a[i] + sf[i]);            // y3 unrounded
        v[i] = (f0[i] + f1[i]) + (sf[i] + r);
        ss = fmaf(v[i], v[i], ss);
    }
    ss += __shfl_xor(ss, 1, 64);
    ss += __shfl_xor(ss, 2, 64);
    ss += __shfl_xor(ss, 4, 64);
    float inv = 1.0f / fmaxf(sqrtf(ss), 1e-12f);
    float4* op = (float4*)&out[idx];
    op[0] = make_float4(v[0] * inv, v[1] * inv, v[2] * inv, v[3] * inv);
    op[1] = make_float4(v[4] * inv, v[5] * inv, v[6] * inv, v[7] * inv);
}

// ---------------- epilogue A: l2norm(acc)  (acc fp32, may alias out) ----------------
__global__ void k_final_acc(const float* __restrict__ acc, float* __restrict__ out) {
    int lane = threadIdx.x & 63;
    int c = (blockIdx.x * 256 + threadIdx.x) >> 6;
    if (c >= N_CNT) return;
    int idx = c * 64 + lane;
    float v = acc[idx];
    float ss = v * v;
    #pragma unroll
    for (int m = 32; m >= 1; m >>= 1) ss += __shfl_xor(ss, m, 64);
    out[idx] = v / fmaxf(sqrtf(ss), 1e-12f);
}

extern "C" void kernel_launch(void* const* d_in, const int* in_sizes, int n_in,
                              void* d_out, int out_size, void* d_ws, size_t ws_size,
                              hipStream_t stream) {
    const int*   edge_src   = (const int*)  d_in[0];
    const int*   edge_dst   = (const int*)  d_in[1];
    const float* edge_attr  = (const float*)d_in[2];
    const float* user_w     = (const float*)d_in[3];
    const float* artist_w   = (const float*)d_in[4];
    const float* album_w    = (const float*)d_in[5];
    const float* item_audio = (const float*)d_in[6];
    const int*   artist_ids = (const int*)  d_in[7];
    const int*   album_ids  = (const int*)  d_in[8];
    const float* Wp         = (const float*)d_in[9];
    const float* bp         = (const float*)d_in[10];
    const float* W1         = (const float*)d_in[11];
    const float* b1         = (const float*)d_in[12];
    const float* W2         = (const float*)d_in[13];
    const float* b2         = (const float*)d_in[14];

    char* p = (char*)d_ws;
    auto carve = [&](size_t bytes) -> void* {
        void* q = (void*)p;
        p += (bytes + 255) & ~(size_t)255;
        return q;
    };
    // common carve (~31 MB)
    float* dis    = (float*)carve((size_t)N_CNT * 4);
    int*   offs   = (int*)  carve((size_t)(N_CNT + 1) * 4);
    int*   gcur   = (int*)  carve((size_t)NBUCK * 4);
    int2*  csr    = (int2*) carve((size_t)2 * E_CNT * 8);
    ubf*   metabuf= (ubf*)  carve((size_t)I_CNT * 64 * 2);  // 12.8 MB bf16
    const size_t YB = (size_t)N_CNT * 64 * 2;      // 38.4 MB per bf16 y buffer
    const size_t EBUF = (size_t)NBUCK * BCAP * 8;  // 28.8 MB entry buffer
    size_t used = (size_t)(p - (char*)d_ws);
    // Path B (no acc RMW) needs y0,y1,y2 bf16 in ws; ebuf aliases y2 (dead
    // until prop round 2). Else ping-pong + fp32 acc in d_out.
    int no_acc = (ws_size >= used + 3 * YB + (size_t)4096) ? 1 : 0;
    ubf *y0, *y1, *y2;
    uint2* ebuf;
    float* acc = nullptr;
    if (no_acc) {
        y0 = (ubf*)carve(YB);
        y1 = (ubf*)carve(YB);
        y2 = (ubf*)carve(YB);
        ebuf = (uint2*)y2;             // alias: 38.4MB >= 28.8MB
    } else {
        y0 = (ubf*)carve(YB);
        y1 = (ubf*)carve(YB);
        y2 = y0;
        acc = (float*)d_out;           // fp32 accumulator lives in d_out
        ebuf = (uint2*)carve(EBUF);
    }
    (void)in_sizes; (void)n_in; (void)out_size;

    hipMemsetAsync(gcur, 0, (size_t)NBUCK * 4, stream);
    // bin1 blocks first (atomic-latency role), meta role blocks fill behind
    k_bin1 <<<NB_BIN1 + NB_META5, 512, 0, stream>>>(
        edge_src, edge_dst, edge_attr, W1, b1, W2, b2, ebuf, gcur,
        artist_w, album_w, artist_ids, album_ids, metabuf);
    k_bin2 <<<NBUCK, 1024, 0, stream>>>(ebuf, gcur, offs, csr, dis);
    k_users<<<1024, 256, 0, stream>>>(user_w, dis, y0, acc, no_acc ? 0 : 1);
    k_items<<<NB_I, 256, 0, stream>>>(item_audio, metabuf, Wp, bp, dis,
                                      y0 + (size_t)U_CNT * 64,
                                      no_acc ? nullptr : acc + (size_t)U_CNT * 64,
                                      no_acc ? 0 : 1);
    // 8 nodes per wave -> N/8 waves -> N/32 blocks of 256
    const int PROP_BLKS = N_CNT / 32;    // 9375
    if (no_acc) {
        k_prop<<<PROP_BLKS, 256, 0, stream>>>(offs, csr, dis, y0, y1, nullptr, 0);
        k_prop<<<PROP_BLKS, 256, 0, stream>>>(offs, csr, dis, y1, y2, nullptr, 0);
        k_prop_fin<<<PROP_BLKS, 256, 0, stream>>>(offs, csr, dis, y0, y1, y2,
                                                  (float*)d_out);
    } else {
        // y0 -> y1 -> y0 -> y1 (bf16), accumulating fp32 into acc (= d_out)
        k_prop<<<PROP_BLKS, 256, 0, stream>>>(offs, csr, dis, y0, y1, acc, 1);
        k_prop<<<PROP_BLKS, 256, 0, stream>>>(offs, csr, dis, y1, y0, acc, 1);
        k_prop<<<PROP_BLKS, 256, 0, stream>>>(offs, csr, dis, y0, y1, acc, 1);
        k_final_acc<<<N_CNT / 4, 256, 0, stream>>>(acc, (float*)d_out);
    }
}